// Round 1
// baseline (80975.964 us; speedup 1.0000x reference)
//
#include <hip/hip_runtime.h>
#include <hip/hip_bf16.h>

#define Bn 64
#define Sn 256
#define In 512
#define Hn 80
#define Tn 600
#define Cn 512
#define LOCn 8
#define Kn 21
#define Pn 11
#define XD (In + Hn)   /* 592 */
#define G3 (3 * Cn)    /* 1536 */
#define CH (Cn / 2)    /* 256 */

// ---- ws layout (floats) ----
enum {
  OFF_WIT = 0,                          // [XD][G3]
  OFF_WHT = OFF_WIT + XD * G3,          // [Cn][G3]
  OFF_W1T = OFF_WHT + Cn * G3,          // [Cn][Cn]
  OFF_W2T = OFF_W1T + Cn * Cn,          // [Cn][LOC*K]
  OFF_BI  = OFF_W2T + Cn * (LOCn * Kn),
  OFF_BH  = OFF_BI + G3,
  OFF_B1  = OFF_BH + G3,
  OFF_LW  = OFF_B1 + Cn,                // [LOC][K]
  OFF_P   = OFF_LW + LOCn * Kn,         // [CH][LOC]
  OFF_D   = OFF_P + CH * LOCn,          // [CH][LOC]
  OFF_DB  = OFF_D + CH * LOCn,
  OFF_AGG = OFF_DB + CH,
  OFF_PRI = OFF_AGG + CH,
  OFF_FLAG = OFF_PRI + Pn,
  WS_FLOATS = OFF_FLAG + 1
};

__device__ __forceinline__ float ld_any(const void* p, long long i, int bf) {
  if (bf) {
    unsigned v = ((const unsigned short*)p)[i];
    return __uint_as_float(v << 16);
  }
  return ((const float*)p)[i];
}

__device__ __forceinline__ float fast_exp(float x) {
  return __builtin_amdgcn_exp2f(x * 1.4426950408889634f);
}
__device__ __forceinline__ float fast_sigmoid(float x) {
  return __builtin_amdgcn_rcpf(1.f + fast_exp(-x));
}
__device__ __forceinline__ float fast_tanh(float x) {
  float u = __builtin_amdgcn_exp2f(x * 2.8853900817779268f); // e^(2x)
  return 1.f - 2.f * __builtin_amdgcn_rcpf(u + 1.f);
}
__device__ __forceinline__ float fast_log(float x) {
  return __builtin_amdgcn_logf(x) * 0.6931471805599453f;
}

// ---- dtype probe: mask is all-ones; fp32 word = 0x3F800000, bf16 pair = 0x3F803F80
__global__ void k_flag(const void* mask, float* ws) {
  if (threadIdx.x == 0 && blockIdx.x == 0) {
    unsigned w = *(const unsigned*)mask;
    ((int*)(ws + OFF_FLAG))[0] = (w == 0x3F803F80u) ? 1 : 0;
  }
}

// ---- transpose/convert all weights into ws (fp32, output-column-major for coalescing)
__global__ void k_prep(const void* wi, const void* wh, const void* gbi, const void* gbh,
                       const void* lcw, const void* lpw, const void* w1, const void* kb1,
                       const void* w2, const void* dw, const void* ddb, const void* aggw,
                       const void* pri, float* ws) {
  const int bf = ((const int*)(ws + OFF_FLAG))[0];
  const int tid = blockIdx.x * blockDim.x + threadIdx.x;
  const int nT = gridDim.x * blockDim.x;
  for (int x = tid; x < G3 * XD; x += nT) {
    int c = x % G3, k = x / G3;
    ws[OFF_WIT + (size_t)k * G3 + c] = ld_any(wi, (long long)c * XD + k, bf);
  }
  for (int x = tid; x < G3 * Cn; x += nT) {
    int c = x % G3, k = x / G3;
    ws[OFF_WHT + (size_t)k * G3 + c] = ld_any(wh, (long long)c * Cn + k, bf);
  }
  for (int x = tid; x < Cn * Cn; x += nT) {
    int c = x % Cn, k = x / Cn;
    ws[OFF_W1T + (size_t)k * Cn + c] = ld_any(w1, (long long)c * Cn + k, bf);
  }
  for (int x = tid; x < (LOCn * Kn) * Cn; x += nT) {
    int c = x % (LOCn * Kn), k = x / (LOCn * Kn);
    ws[OFF_W2T + (size_t)k * (LOCn * Kn) + c] = ld_any(w2, (long long)c * Cn + k, bf);
  }
  for (int x = tid; x < G3; x += nT) ws[OFF_BI + x] = ld_any(gbi, x, bf);
  for (int x = tid; x < G3; x += nT) ws[OFF_BH + x] = ld_any(gbh, x, bf);
  for (int x = tid; x < Cn; x += nT) ws[OFF_B1 + x] = ld_any(kb1, x, bf);
  for (int x = tid; x < LOCn * Kn; x += nT) ws[OFF_LW + x] = ld_any(lcw, x, bf);
  for (int x = tid; x < CH * LOCn; x += nT) ws[OFF_P + x] = ld_any(lpw, x, bf);
  for (int x = tid; x < CH * LOCn; x += nT) ws[OFF_D + x] = ld_any(dw, x, bf);
  for (int x = tid; x < CH; x += nT) ws[OFF_DB + x] = ld_any(ddb, x, bf);
  for (int x = tid; x < CH; x += nT) ws[OFF_AGG + x] = ld_any(aggw, x, bf);
  for (int x = tid; x < Pn; x += nT) ws[OFF_PRI + x] = ld_any(pri, x, bf);
}

// ---- persistent per-batch kernel: one block per batch row, full T loop inside
__global__ __launch_bounds__(1024) void k_aligner(
    const void* __restrict__ enc_, const void* __restrict__ mask_,
    const void* __restrict__ gt_, const float* __restrict__ ws,
    void* __restrict__ out_) {
  const int b = blockIdx.x;
  const int tid = threadIdx.x;
  const int bf = ((const int*)(ws + OFF_FLAG))[0];

  const float* WiT = ws + OFF_WIT;
  const float* WhT = ws + OFF_WHT;
  const float* W1T = ws + OFF_W1T;
  const float* W2T = ws + OFF_W2T;
  const float* gbi = ws + OFF_BI;
  const float* gbh = ws + OFF_BH;
  const float* kb1 = ws + OFF_B1;
  const float* lw  = ws + OFF_LW;
  const float* Pw  = ws + OFF_P;
  const float* Dw  = ws + OFF_D;
  const float* dbv = ws + OFF_DB;
  const float* agg = ws + OFF_AGG;
  const float* prw = ws + OFF_PRI;

  __shared__ float sA[Sn + Kn - 1];   // padded alpha: [10..265] = alpha, rest 0
  __shared__ float sX[XD];
  __shared__ float sH[Cn];
  __shared__ float sQ[Cn];
  __shared__ float sT1[Cn];
  __shared__ float sDk[LOCn * Kn];
  __shared__ float sFL[LOCn][Sn];
  __shared__ float sFD[LOCn][Sn];
  __shared__ float sPri[Sn];
  __shared__ float sG[6 * Cn];        // gx(3C) then gh(3C)
  __shared__ float sR[1024];
  __shared__ float sMask[Sn];
  __shared__ float sRed2[8];

  for (int x = tid; x < Sn + Kn - 1; x += 1024) sA[x] = 0.f;
  for (int x = tid; x < Cn; x += 1024) sH[x] = 0.f;
  for (int x = tid; x < Sn; x += 1024) sMask[x] = ld_any(mask_, (long long)b * Sn + x, bf);
  if (tid == 0) sA[Kn / 2] = 1.f;     // alpha0[0] = 1
  __syncthreads();

  for (int t = 0; t < Tn; ++t) {
    // ---- stage 1: context prev = enc^T alpha  (+ frame load)
    {
      int i = tid & (In - 1);
      int half = tid >> 9;
      int s0 = half << 7;
      float acc = 0.f;
      if (bf) {
        const unsigned short* enc = (const unsigned short*)enc_ + (size_t)b * Sn * In + i;
        #pragma unroll 4
        for (int s = s0; s < s0 + 128; ++s)
          acc = fmaf(__uint_as_float(((unsigned)enc[(size_t)s * In]) << 16), sA[10 + s], acc);
      } else {
        const float* enc = (const float*)enc_ + (size_t)b * Sn * In + i;
        #pragma unroll 4
        for (int s = s0; s < s0 + 128; ++s)
          acc = fmaf(enc[(size_t)s * In], sA[10 + s], acc);
      }
      sR[tid] = acc;
    }
    __syncthreads();
    if (tid < In) sX[Hn + tid] = sR[tid] + sR[tid + In];
    else if (tid < In + Hn) sX[tid - In] = ld_any(gt_, ((size_t)b * Tn + t) * Hn + (tid - In), bf);
    __syncthreads();

    // ---- stage 2: gx (tid<512) and gh (tid>=512), 3 gates each
    {
      int c = tid & (Cn - 1);
      if (tid < Cn) {
        float a0 = gbi[c], a1 = gbi[Cn + c], a2 = gbi[2 * Cn + c];
        for (int k = 0; k < XD; ++k) {
          float xv = sX[k];
          const float* w = WiT + (size_t)k * G3 + c;
          a0 = fmaf(xv, w[0], a0);
          a1 = fmaf(xv, w[Cn], a1);
          a2 = fmaf(xv, w[2 * Cn], a2);
        }
        sG[c] = a0; sG[Cn + c] = a1; sG[2 * Cn + c] = a2;
      } else {
        float a0 = gbh[c], a1 = gbh[Cn + c], a2 = gbh[2 * Cn + c];
        for (int k = 0; k < Cn; ++k) {
          float hv = sH[k];
          const float* w = WhT + (size_t)k * G3 + c;
          a0 = fmaf(hv, w[0], a0);
          a1 = fmaf(hv, w[Cn], a1);
          a2 = fmaf(hv, w[2 * Cn], a2);
        }
        sG[3 * Cn + c] = a0; sG[4 * Cn + c] = a1; sG[5 * Cn + c] = a2;
      }
    }
    __syncthreads();

    // ---- stage 3: gates -> query (tid<512); loc conv + prior conv (tid>=512)
    if (tid < Cn) {
      int c = tid;
      float r = fast_sigmoid(sG[c] + sG[3 * Cn + c]);
      float z = fast_sigmoid(sG[Cn + c] + sG[4 * Cn + c]);
      float n = fast_tanh(sG[2 * Cn + c] + r * sG[5 * Cn + c]);
      sQ[c] = (1.f - z) * n + z * sH[c];
    } else {
      int j = tid - Cn;
      #pragma unroll
      for (int rr = 0; rr < 4; ++rr) {
        int idx = j + (rr << 9);
        int l = idx >> 8, s = idx & (Sn - 1);
        float acc = 0.f;
        #pragma unroll
        for (int k = 0; k < Kn; ++k) acc = fmaf(lw[l * Kn + k], sA[s + k], acc);
        sFL[l][s] = acc;
      }
      if (j < Sn) {
        float acc = 0.f;
        #pragma unroll
        for (int k = 0; k < Pn; ++k) acc = fmaf(prw[k], sA[j + k], acc);
        sPri[j] = acc;
      }
    }
    __syncthreads();

    // ---- stage 4: t1 = tanh(q @ W1^T + b1) (tid<512); state <- query (tid>=512)
    if (tid < Cn) {
      int c = tid;
      float acc = kb1[c];
      for (int k = 0; k < Cn; ++k) acc = fmaf(sQ[k], W1T[(size_t)k * Cn + c], acc);
      sT1[c] = fast_tanh(acc);
    } else {
      sH[tid - Cn] = sQ[tid - Cn];
    }
    __syncthreads();

    // ---- stage 5: dkern = t1 @ W2^T  (672 threads: 4 k-quarters x 168 outputs)
    if (tid < 672) {
      int kq = tid / 168;
      int j = tid - kq * 168;
      int k0 = kq << 7;
      float acc = 0.f;
      for (int k = k0; k < k0 + 128; ++k)
        acc = fmaf(sT1[k], W2T[(size_t)k * (LOCn * Kn) + j], acc);
      sR[tid] = acc;
    }
    __syncthreads();
    if (tid < LOCn * Kn) sDk[tid] = sR[tid] + sR[tid + 168] + sR[tid + 336] + sR[tid + 504];
    __syncthreads();

    // ---- stage 6: dynamic conv feat
    #pragma unroll
    for (int rr = 0; rr < 2; ++rr) {
      int idx = tid + (rr << 10);
      int l = idx >> 8, s = idx & (Sn - 1);
      float acc = 0.f;
      #pragma unroll
      for (int k = 0; k < Kn; ++k) acc = fmaf(sDk[l * Kn + k], sA[s + k], acc);
      sFD[l][s] = acc;
    }
    __syncthreads();

    // ---- stage 7: energy partials: 4 channel-quarters x 256 positions
    {
      int s = tid & (Sn - 1);
      int q = tid >> 8;
      float fl0[LOCn], fd0[LOCn];
      #pragma unroll
      for (int l = 0; l < LOCn; ++l) { fl0[l] = sFL[l][s]; fd0[l] = sFD[l][s]; }
      float e = 0.f;
      int c0 = q << 6;
      for (int c = c0; c < c0 + 64; ++c) {
        float sc = dbv[c];
        #pragma unroll
        for (int l = 0; l < LOCn; ++l) {
          sc = fmaf(Pw[c * LOCn + l], fl0[l], sc);
          sc = fmaf(Dw[c * LOCn + l], fd0[l], sc);
        }
        e = fmaf(agg[c], fast_tanh(sc), e);
      }
      sR[tid] = e;
    }
    __syncthreads();

    // ---- stage 8: combine + prior + mask + softmax + write alpha/out
    float eVal = -__builtin_inff();
    if (tid < Sn) {
      eVal = sR[tid] + sR[tid + 256] + sR[tid + 512] + sR[tid + 768];
      eVal += fast_log(sPri[tid] + 1e-5f);
      if (!(sMask[tid] > 0.f)) eVal = -__builtin_inff();
      float m = eVal;
      #pragma unroll
      for (int off = 32; off > 0; off >>= 1) m = fmaxf(m, __shfl_xor(m, off, 64));
      if ((tid & 63) == 0) sRed2[tid >> 6] = m;
    }
    __syncthreads();
    float exv = 0.f;
    if (tid < Sn) {
      float M = fmaxf(fmaxf(sRed2[0], sRed2[1]), fmaxf(sRed2[2], sRed2[3]));
      exv = fast_exp(eVal - M);
      float ssum = exv;
      #pragma unroll
      for (int off = 32; off > 0; off >>= 1) ssum += __shfl_xor(ssum, off, 64);
      if ((tid & 63) == 0) sRed2[4 + (tid >> 6)] = ssum;
    }
    __syncthreads();
    if (tid < Sn) {
      float Z = sRed2[4] + sRed2[5] + sRed2[6] + sRed2[7];
      float a = exv * __builtin_amdgcn_rcpf(Z);
      sA[10 + tid] = a;
      size_t oi = ((size_t)b * Tn + t) * Sn + tid;
      if (bf) ((__hip_bfloat16*)out_)[oi] = __float2bfloat16(a);
      else ((float*)out_)[oi] = a;
    }
    __syncthreads();
  }
}

extern "C" void kernel_launch(void* const* d_in, const int* in_sizes, int n_in,
                              void* d_out, int out_size, void* d_ws, size_t ws_size,
                              hipStream_t stream) {
  float* ws = (float*)d_ws;
  // d_in: 0 encodings, 1 mask, 2 gt, 3 gru_wi, 4 gru_wh, 5 gru_bi, 6 gru_bh,
  //       7 loc_conv_w, 8 loc_proj_w, 9 kernel_w1, 10 kernel_b1, 11 kernel_w2,
  //       12 dyn_w, 13 dyn_b, 14 agg_w, 15 prior
  k_flag<<<1, 64, 0, stream>>>(d_in[1], ws);
  k_prep<<<1024, 256, 0, stream>>>(d_in[3], d_in[4], d_in[5], d_in[6],
                                   d_in[7], d_in[8], d_in[9], d_in[10],
                                   d_in[11], d_in[12], d_in[13], d_in[14],
                                   d_in[15], ws);
  k_aligner<<<Bn, 1024, 0, stream>>>(d_in[0], d_in[1], d_in[2], ws, d_out);
}

// Round 2
// 58266.943 us; speedup vs baseline: 1.3897x; 1.3897x over previous
//
#include <hip/hip_runtime.h>
#include <hip/hip_bf16.h>

#define Bn 64
#define Sn 256
#define In 512
#define Hn 80
#define Tn 600
#define Cn 512
#define LOCn 8
#define Kn 21
#define Pn 11
#define G3 1536

// ---- ws layout (dword offsets) ----
enum : unsigned {
  OFF_WHPK     = 0u,                       // [256 kp][1536]  bf16x2 pairs over h-dim
  OFF_W1PK     = OFF_WHPK + 256u * 1536u,  // [256 kp][512]
  OFF_W2PK     = OFF_W1PK + 256u * 512u,   // [256 kp][168]
  OFF_WIFPK    = OFF_W2PK + 256u * 168u,   // [40 jp][1536]  frame part of gru_wi
  OFF_WIPREVPK = OFF_WIFPK + 40u * 1536u,  // [256 kp][1536] prev part (fallback path)
  OFF_BI       = OFF_WIPREVPK + 256u * 1536u,
  OFF_BH       = OFF_BI + 1536u,
  OFF_B1       = OFF_BH + 1536u,
  OFF_LW       = OFF_B1 + 512u,
  OFF_PW       = OFF_LW + 176u,
  OFF_DW       = OFF_PW + 2048u,
  OFF_DB       = OFF_DW + 2048u,
  OFF_AGG      = OFF_DB + 256u,
  OFF_PRI      = OFF_AGG + 256u,
  OFF_FLAG     = OFF_PRI + 16u,
  OFF_WIPT     = 1030400u,                  // fp32 [512 i][1536 c] = wi[c][80+i]
  OFF_ENCW     = OFF_WIPT + 512u * 1536u,   // [b][128 sp][1536] bf16x2 pairs over s
  WS_END_ENCW  = OFF_ENCW + 64u * 128u * 1536u
};

__device__ __forceinline__ float ld_any(const void* p, long long i, int bf) {
  if (bf) {
    unsigned v = ((const unsigned short*)p)[i];
    return __uint_as_float(v << 16);
  }
  return ((const float*)p)[i];
}
__device__ __forceinline__ unsigned short bf_rne(float f) {
  unsigned u = __float_as_uint(f);
  unsigned r = (u + 0x7fffu + ((u >> 16) & 1u)) >> 16;
  return (unsigned short)r;
}
__device__ __forceinline__ unsigned pack2(float a, float b) {
  return (unsigned)bf_rne(a) | ((unsigned)bf_rne(b) << 16);
}
__device__ __forceinline__ float pklo(unsigned w) { return __uint_as_float(w << 16); }
__device__ __forceinline__ float pkhi(unsigned w) { return __uint_as_float(w & 0xffff0000u); }

__device__ __forceinline__ float fast_exp(float x) {
  return __builtin_amdgcn_exp2f(x * 1.4426950408889634f);
}
__device__ __forceinline__ float fast_sigmoid(float x) {
  return __builtin_amdgcn_rcpf(1.f + fast_exp(-x));
}
__device__ __forceinline__ float fast_tanh(float x) {
  float u = __builtin_amdgcn_exp2f(x * 2.8853900817779268f);
  return 1.f - 2.f * __builtin_amdgcn_rcpf(u + 1.f);
}
__device__ __forceinline__ float fast_log(float x) {
  return __builtin_amdgcn_logf(x) * 0.6931471805599453f;
}

__global__ void k_flag(const void* mask, float* ws) {
  if (threadIdx.x == 0 && blockIdx.x == 0) {
    unsigned w = *(const unsigned*)mask;
    ((int*)(ws + OFF_FLAG))[0] = (w == 0x3F803F80u) ? 1 : 0;
  }
}

__global__ void k_prep(const void* wi, const void* wh, const void* gbi, const void* gbh,
                       const void* lcw, const void* lpw, const void* w1, const void* kb1,
                       const void* w2, const void* dw, const void* ddb, const void* aggw,
                       const void* pri, float* wsf, unsigned* U) {
  const int bf = ((const int*)(wsf + OFF_FLAG))[0];
  const int tid = blockIdx.x * blockDim.x + threadIdx.x;
  const int nT = gridDim.x * blockDim.x;
  for (int x = tid; x < 256 * 1536; x += nT) {
    int kp = x / 1536, c = x % 1536;
    U[OFF_WHPK + x] = pack2(ld_any(wh, (long long)c * Cn + 2 * kp, bf),
                            ld_any(wh, (long long)c * Cn + 2 * kp + 1, bf));
  }
  for (int x = tid; x < 256 * 512; x += nT) {
    int kp = x / 512, c = x % 512;
    U[OFF_W1PK + x] = pack2(ld_any(w1, (long long)c * Cn + 2 * kp, bf),
                            ld_any(w1, (long long)c * Cn + 2 * kp + 1, bf));
  }
  for (int x = tid; x < 256 * 168; x += nT) {
    int kp = x / 168, j = x % 168;
    U[OFF_W2PK + x] = pack2(ld_any(w2, (long long)j * Cn + 2 * kp, bf),
                            ld_any(w2, (long long)j * Cn + 2 * kp + 1, bf));
  }
  for (int x = tid; x < 40 * 1536; x += nT) {
    int jp = x / 1536, c = x % 1536;
    U[OFF_WIFPK + x] = pack2(ld_any(wi, (long long)c * (In + Hn) + 2 * jp, bf),
                             ld_any(wi, (long long)c * (In + Hn) + 2 * jp + 1, bf));
  }
  for (int x = tid; x < 256 * 1536; x += nT) {
    int kp = x / 1536, c = x % 1536;
    U[OFF_WIPREVPK + x] = pack2(ld_any(wi, (long long)c * (In + Hn) + Hn + 2 * kp, bf),
                                ld_any(wi, (long long)c * (In + Hn) + Hn + 2 * kp + 1, bf));
  }
  for (int x = tid; x < 512 * 1536; x += nT) {
    int i = x / 1536, c = x % 1536;
    wsf[OFF_WIPT + x] = ld_any(wi, (long long)c * (In + Hn) + Hn + i, bf);
  }
  for (int x = tid; x < G3; x += nT) wsf[OFF_BI + x] = ld_any(gbi, x, bf);
  for (int x = tid; x < G3; x += nT) wsf[OFF_BH + x] = ld_any(gbh, x, bf);
  for (int x = tid; x < Cn; x += nT) wsf[OFF_B1 + x] = ld_any(kb1, x, bf);
  for (int x = tid; x < LOCn * Kn; x += nT) wsf[OFF_LW + x] = ld_any(lcw, x, bf);
  for (int x = tid; x < 256 * LOCn; x += nT) wsf[OFF_PW + x] = ld_any(lpw, x, bf);
  for (int x = tid; x < 256 * LOCn; x += nT) wsf[OFF_DW + x] = ld_any(dw, x, bf);
  for (int x = tid; x < 256; x += nT) wsf[OFF_DB + x] = ld_any(ddb, x, bf);
  for (int x = tid; x < 256; x += nT) wsf[OFF_AGG + x] = ld_any(aggw, x, bf);
  for (int x = tid; x < Pn; x += nT) wsf[OFF_PRI + x] = ld_any(pri, x, bf);
}

// ENCW[b, s, c] = sum_i enc[b,s,i] * wi[c, 80+i], packed bf16 pairs over s.
__global__ __launch_bounds__(1024) void k_encw(const void* __restrict__ enc_,
                                               const float* __restrict__ wsf,
                                               unsigned* __restrict__ U) {
  const int b = blockIdx.x >> 2, chunk = blockIdx.x & 3;
  const int bf = ((const int*)(wsf + OFF_FLAG))[0];
  const int tid = threadIdx.x;
  const int r = tid >> 8, c0 = tid & 255;
  const int s0 = chunk * 64 + r * 16;
  const float* WiPT = wsf + OFF_WIPT;
  for (int g = 0; g < 6; ++g) {
    int c = c0 + (g << 8);
    float acc[16];
    #pragma unroll
    for (int j = 0; j < 16; ++j) acc[j] = 0.f;
    #pragma unroll 4
    for (int i = 0; i < In; ++i) {
      float w = WiPT[(size_t)i * G3 + c];
      #pragma unroll
      for (int j = 0; j < 16; ++j)
        acc[j] = fmaf(w, ld_any(enc_, ((long long)b * Sn + (s0 + j)) * In + i, bf), acc[j]);
    }
    unsigned* dst = U + OFF_ENCW + (size_t)b * 128 * G3 + c;
    #pragma unroll
    for (int jj = 0; jj < 8; ++jj)
      dst[(size_t)((s0 >> 1) + jj) * G3] = pack2(acc[2 * jj], acc[2 * jj + 1]);
  }
}

__global__ __launch_bounds__(1024) void k_aligner(
    const void* __restrict__ enc_, const void* __restrict__ mask_,
    const void* __restrict__ gt_, const float* __restrict__ wsf,
    const unsigned* __restrict__ U, void* __restrict__ out_, int use_encw) {
  const int b = blockIdx.x;
  const int tid = threadIdx.x;
  const int bf = ((const int*)(wsf + OFF_FLAG))[0];

  const float* BI = wsf + OFF_BI;
  const float* BH = wsf + OFF_BH;
  const float* B1 = wsf + OFF_B1;
  const float* lw = wsf + OFF_LW;
  const float* Pw = wsf + OFF_PW;
  const float* Dw = wsf + OFF_DW;
  const float* dbv = wsf + OFF_DB;
  const float* agg = wsf + OFF_AGG;
  const float* prw = wsf + OFF_PRI;

  __shared__ __align__(16) float sA[280];     // alpha padded, data at [10..265]
  __shared__ __align__(16) float sXf[80];     // frame
  __shared__ __align__(16) float sPrev[512];  // fallback context
  __shared__ __align__(16) float sH[512];
  __shared__ __align__(16) float sT1[512];
  __shared__ __align__(16) float sXr[512], sXz[512], sXn[512];
  __shared__ __align__(16) float sHr[512], sHz[512], sHnM[512], sHnP[512];
  __shared__ __align__(16) float sDk[176];
  __shared__ __align__(16) float sFL[LOCn][Sn];
  __shared__ __align__(16) float sFD[LOCn][Sn];
  __shared__ __align__(16) float sPri[Sn];
  __shared__ __align__(16) float sMask[Sn];
  __shared__ __align__(16) float sR[1024];
  __shared__ float sRed2[8];

  for (int x = tid; x < 280; x += 1024) sA[x] = 0.f;
  for (int x = tid; x < Cn; x += 1024) sH[x] = 0.f;
  for (int x = tid; x < Sn; x += 1024) sMask[x] = ld_any(mask_, (long long)b * Sn + x, bf);
  if (tid == 0) sA[Kn / 2] = 1.f;
  __syncthreads();

  const int Pp = use_encw ? 132 : 0;   // hn k-pairs moved to the gx half for balance
  const int n3 = 256 - Pp;
  const int n1 = use_encw ? 128 : 256;

  for (int t = 0; t < Tn; ++t) {
    // ---- S0: frame load (+ fallback context) ----
    if (!use_encw) {
      int i = tid & (In - 1);
      int s0 = (tid >> 9) << 7;
      float acc = 0.f;
      if (bf) {
        const unsigned short* enc = (const unsigned short*)enc_ + (size_t)b * Sn * In + i;
        #pragma unroll 4
        for (int s = s0; s < s0 + 128; ++s)
          acc = fmaf(__uint_as_float(((unsigned)enc[(size_t)s * In]) << 16), sA[10 + s], acc);
      } else {
        const float* enc = (const float*)enc_ + (size_t)b * Sn * In + i;
        #pragma unroll 4
        for (int s = s0; s < s0 + 128; ++s)
          acc = fmaf(enc[(size_t)s * In], sA[10 + s], acc);
      }
      sR[tid] = acc;
    }
    if (tid < Hn) sXf[tid] = ld_any(gt_, ((long long)b * Tn + t) * Hn + tid, bf);
    __syncthreads();
    if (!use_encw) {
      if (tid < In) sPrev[tid] = sR[tid] + sR[tid + In];
      __syncthreads();
    }

    // ---- S1: big dots ----
    if (tid < Cn) {
      const int c = tid;
      float xr = BI[c], xz = BI[c + 512], xn = BI[c + 1024];
      {
        const unsigned* mf = U + OFF_WIFPK + c;
        const float2* af = (const float2*)sXf;
        #pragma unroll 4
        for (int kp = 0; kp < 40; ++kp) {
          float2 a = af[kp];
          unsigned w0 = mf[(size_t)kp * G3];
          unsigned w1 = mf[(size_t)kp * G3 + 512];
          unsigned w2 = mf[(size_t)kp * G3 + 1024];
          xr = fmaf(pklo(w0), a.x, fmaf(pkhi(w0), a.y, xr));
          xz = fmaf(pklo(w1), a.x, fmaf(pkhi(w1), a.y, xz));
          xn = fmaf(pklo(w2), a.x, fmaf(pkhi(w2), a.y, xn));
        }
      }
      {
        const unsigned* mm = use_encw ? (U + OFF_ENCW + (size_t)b * 128 * G3 + c)
                                      : (U + OFF_WIPREVPK + c);
        const float2* am = use_encw ? (const float2*)(sA + 10) : (const float2*)sPrev;
        #pragma unroll 4
        for (int kp = 0; kp < n1; ++kp) {
          float2 a = am[kp];
          unsigned w0 = mm[(size_t)kp * G3];
          unsigned w1 = mm[(size_t)kp * G3 + 512];
          unsigned w2 = mm[(size_t)kp * G3 + 1024];
          xr = fmaf(pklo(w0), a.x, fmaf(pkhi(w0), a.y, xr));
          xz = fmaf(pklo(w1), a.x, fmaf(pkhi(w1), a.y, xz));
          xn = fmaf(pklo(w2), a.x, fmaf(pkhi(w2), a.y, xn));
        }
      }
      {
        float hp = 0.f;
        const unsigned* mh = U + OFF_WHPK + (size_t)n3 * G3 + 1024 + c;
        const float2* ah = (const float2*)sH + n3;
        #pragma unroll 4
        for (int kp = 0; kp < Pp; ++kp) {
          float2 a = ah[kp];
          unsigned w = mh[(size_t)kp * G3];
          hp = fmaf(pklo(w), a.x, fmaf(pkhi(w), a.y, hp));
        }
        sHnP[c] = hp;
      }
      sXr[c] = xr; sXz[c] = xz; sXn[c] = xn;
    } else {
      const int c = tid - Cn;
      float hr = BH[c], hz = BH[c + 512], hn = BH[c + 1024];
      const unsigned* mh = U + OFF_WHPK + c;
      const float2* ah = (const float2*)sH;
      #pragma unroll 4
      for (int kp = 0; kp < n3; ++kp) {
        float2 a = ah[kp];
        unsigned w0 = mh[(size_t)kp * G3];
        unsigned w1 = mh[(size_t)kp * G3 + 512];
        unsigned w2 = mh[(size_t)kp * G3 + 1024];
        hr = fmaf(pklo(w0), a.x, fmaf(pkhi(w0), a.y, hr));
        hz = fmaf(pklo(w1), a.x, fmaf(pkhi(w1), a.y, hz));
        hn = fmaf(pklo(w2), a.x, fmaf(pkhi(w2), a.y, hn));
      }
      #pragma unroll 4
      for (int kp = n3; kp < 256; ++kp) {
        float2 a = ah[kp];
        unsigned w0 = mh[(size_t)kp * G3];
        unsigned w1 = mh[(size_t)kp * G3 + 512];
        hr = fmaf(pklo(w0), a.x, fmaf(pkhi(w0), a.y, hr));
        hz = fmaf(pklo(w1), a.x, fmaf(pkhi(w1), a.y, hz));
      }
      sHr[c] = hr; sHz[c] = hz; sHnM[c] = hn;
    }
    __syncthreads();

    // ---- S2: gates -> query/state (tid<512); loc conv + prior (tid>=512) ----
    if (tid < Cn) {
      int c = tid;
      float r = fast_sigmoid(sXr[c] + sHr[c]);
      float z = fast_sigmoid(sXz[c] + sHz[c]);
      float n = fast_tanh(sXn[c] + r * (sHnM[c] + sHnP[c]));
      sH[c] = (1.f - z) * n + z * sH[c];
    } else {
      int j = tid - Cn;
      #pragma unroll
      for (int rr = 0; rr < 4; ++rr) {
        int idx = j + (rr << 9);
        int l = idx >> 8, s = idx & (Sn - 1);
        float acc = 0.f;
        #pragma unroll
        for (int k = 0; k < Kn; ++k) acc = fmaf(lw[l * Kn + k], sA[s + k], acc);
        sFL[l][s] = acc;
      }
      if (j < Sn) {
        float acc = 0.f;
        #pragma unroll
        for (int k = 0; k < Pn; ++k) acc = fmaf(prw[k], sA[j + k], acc);
        sPri[j] = acc;
      }
    }
    __syncthreads();

    // ---- S3: t1 = tanh(q @ W1^T + b1), split-k over 2 halves ----
    {
      int c = tid & (Cn - 1), half = tid >> 9;
      const unsigned* m1 = U + OFF_W1PK + (size_t)half * 128 * 512 + c;
      const float2* aq = (const float2*)sH + half * 128;
      float acc = 0.f;
      #pragma unroll 4
      for (int kp = 0; kp < 128; ++kp) {
        float2 a = aq[kp];
        unsigned w = m1[(size_t)kp * 512];
        acc = fmaf(pklo(w), a.x, fmaf(pkhi(w), a.y, acc));
      }
      sR[tid] = acc;
    }
    __syncthreads();
    if (tid < Cn) sT1[tid] = fast_tanh(B1[tid] + sR[tid] + sR[tid + Cn]);
    __syncthreads();

    // ---- S4: dkern = t1 @ W2^T, split-k over 4 quarters ----
    if (tid < 672) {
      int kq = tid / 168, j = tid - kq * 168;
      const unsigned* m2 = U + OFF_W2PK + (size_t)kq * 64 * 168 + j;
      const float2* at = (const float2*)sT1 + kq * 64;
      float acc = 0.f;
      #pragma unroll 4
      for (int kp = 0; kp < 64; ++kp) {
        float2 a = at[kp];
        unsigned w = m2[(size_t)kp * 168];
        acc = fmaf(pklo(w), a.x, fmaf(pkhi(w), a.y, acc));
      }
      sR[tid] = acc;
    }
    __syncthreads();
    if (tid < LOCn * Kn) sDk[tid] = sR[tid] + sR[tid + 168] + sR[tid + 336] + sR[tid + 504];
    __syncthreads();

    // ---- S5: dynamic conv ----
    #pragma unroll
    for (int rr = 0; rr < 2; ++rr) {
      int idx = tid + (rr << 10);
      int l = idx >> 8, s = idx & (Sn - 1);
      float acc = 0.f;
      #pragma unroll
      for (int k = 0; k < Kn; ++k) acc = fmaf(sDk[l * Kn + k], sA[s + k], acc);
      sFD[l][s] = acc;
    }
    __syncthreads();

    // ---- S6: scorer partials (4 channel-quarters x 256 positions) ----
    {
      int s = tid & (Sn - 1);
      int q = tid >> 8;
      float fl0[LOCn], fd0[LOCn];
      #pragma unroll
      for (int l = 0; l < LOCn; ++l) { fl0[l] = sFL[l][s]; fd0[l] = sFD[l][s]; }
      float e = 0.f;
      int c0 = q << 6;
      for (int c = c0; c < c0 + 64; ++c) {
        float sc = dbv[c];
        #pragma unroll
        for (int l = 0; l < LOCn; ++l) {
          sc = fmaf(Pw[c * LOCn + l], fl0[l], sc);
          sc = fmaf(Dw[c * LOCn + l], fd0[l], sc);
        }
        e = fmaf(agg[c], fast_tanh(sc), e);
      }
      sR[tid] = e;
    }
    __syncthreads();

    // ---- S7: energy + softmax + write ----
    float eVal = -__builtin_inff();
    if (tid < Sn) {
      eVal = sR[tid] + sR[tid + 256] + sR[tid + 512] + sR[tid + 768];
      eVal += fast_log(sPri[tid] + 1e-5f);
      if (!(sMask[tid] > 0.f)) eVal = -__builtin_inff();
      float m = eVal;
      #pragma unroll
      for (int off = 32; off > 0; off >>= 1) m = fmaxf(m, __shfl_xor(m, off, 64));
      if ((tid & 63) == 0) sRed2[tid >> 6] = m;
    }
    __syncthreads();
    float exv = 0.f;
    if (tid < Sn) {
      float M = fmaxf(fmaxf(sRed2[0], sRed2[1]), fmaxf(sRed2[2], sRed2[3]));
      exv = fast_exp(eVal - M);
      float ssum = exv;
      #pragma unroll
      for (int off = 32; off > 0; off >>= 1) ssum += __shfl_xor(ssum, off, 64);
      if ((tid & 63) == 0) sRed2[4 + (tid >> 6)] = ssum;
    }
    __syncthreads();
    if (tid < Sn) {
      float Z = sRed2[4] + sRed2[5] + sRed2[6] + sRed2[7];
      float a = exv * __builtin_amdgcn_rcpf(Z);
      sA[10 + tid] = a;
      size_t oi = ((size_t)b * Tn + t) * Sn + tid;
      if (bf) ((__hip_bfloat16*)out_)[oi] = __float2bfloat16(a);
      else ((float*)out_)[oi] = a;
    }
    __syncthreads();
  }
}

extern "C" void kernel_launch(void* const* d_in, const int* in_sizes, int n_in,
                              void* d_out, int out_size, void* d_ws, size_t ws_size,
                              hipStream_t stream) {
  float* wsf = (float*)d_ws;
  unsigned* U = (unsigned*)d_ws;
  const int use_encw = (ws_size >= (size_t)WS_END_ENCW * 4u) ? 1 : 0;
  k_flag<<<1, 64, 0, stream>>>(d_in[1], wsf);
  k_prep<<<1024, 256, 0, stream>>>(d_in[3], d_in[4], d_in[5], d_in[6],
                                   d_in[7], d_in[8], d_in[9], d_in[10],
                                   d_in[11], d_in[12], d_in[13], d_in[14],
                                   d_in[15], wsf, U);
  if (use_encw) k_encw<<<256, 1024, 0, stream>>>(d_in[0], wsf, U);
  k_aligner<<<Bn, 1024, 0, stream>>>(d_in[0], d_in[1], d_in[2], wsf, U, d_out, use_encw);
}

// Round 3
// 42203.088 us; speedup vs baseline: 1.9187x; 1.3806x over previous
//
#include <hip/hip_runtime.h>
#include <hip/hip_bf16.h>

#define Bn 64
#define Sn 256
#define In 512
#define Hn 80
#define Tn 600
#define Cn 512
#define LOCn 8
#define Kn 21
#define Pn 11
#define G3 1536

typedef _Float16 h2 __attribute__((ext_vector_type(2)));

// ---- ws layout (dword offsets) ----
enum : unsigned {
  OFF_WHPK     = 0u,                        // [256 kp][512 c][3 g] half2 pairs over h
  OFF_W1PK     = OFF_WHPK + 256u * 1536u,   // [256 kp][512 c]
  OFF_W2PK     = OFF_W1PK + 256u * 512u,    // [256 kp][168 j]
  OFF_WIFPK    = OFF_W2PK + 256u * 168u,    // [40 jp][512 c][3 g] frame part
  OFF_WIPREVPK = OFF_WIFPK + 40u * 1536u,   // [256 kp][512 c][3 g] prev part (fallback)
  OFF_BI       = OFF_WIPREVPK + 256u * 1536u,
  OFF_BH       = OFF_BI + 1536u,
  OFF_B1       = OFF_BH + 1536u,
  OFF_LW       = OFF_B1 + 512u,
  OFF_PW       = OFF_LW + 176u,
  OFF_DW       = OFF_PW + 2048u,
  OFF_DB       = OFF_DW + 2048u,
  OFF_AGG      = OFF_DB + 256u,
  OFF_PRI      = OFF_AGG + 256u,
  OFF_FLAG     = OFF_PRI + 16u,
  OFF_WIPT     = 1030400u,                  // fp32 [512 i][1536 m] = wi[m][80+i]
  OFF_ENCW     = OFF_WIPT + 512u * 1536u,   // [b][128 sp][512 c][3 g] half2 pairs over s
  WS_END_ENCW  = OFF_ENCW + 64u * 128u * 1536u
};

__device__ __forceinline__ float ld_any(const void* p, long long i, int bf) {
  if (bf) {
    unsigned v = ((const unsigned short*)p)[i];
    return __uint_as_float(v << 16);
  }
  return ((const float*)p)[i];
}
__device__ __forceinline__ unsigned pack_h2(float a, float b) {
  union { h2 h; unsigned u; } x;
  x.h.x = (_Float16)a; x.h.y = (_Float16)b;
  return x.u;
}
__device__ __forceinline__ h2 u_to_h2(unsigned u) {
  union { h2 h; unsigned u; } x; x.u = u; return x.h;
}
__device__ __forceinline__ float dot2f(unsigned w, unsigned a, float acc) {
#if __has_builtin(__builtin_amdgcn_fdot2)
  return __builtin_amdgcn_fdot2(u_to_h2(w), u_to_h2(a), acc, false);
#else
  h2 wv = u_to_h2(w), av = u_to_h2(a);
  return fmaf((float)wv.x, (float)av.x, fmaf((float)wv.y, (float)av.y, acc));
#endif
}

__device__ __forceinline__ float fast_exp(float x) {
  return __builtin_amdgcn_exp2f(x * 1.4426950408889634f);
}
__device__ __forceinline__ float fast_sigmoid(float x) {
  return __builtin_amdgcn_rcpf(1.f + fast_exp(-x));
}
__device__ __forceinline__ float fast_tanh(float x) {
  float u = __builtin_amdgcn_exp2f(x * 2.8853900817779268f);
  return 1.f - 2.f * __builtin_amdgcn_rcpf(u + 1.f);
}
__device__ __forceinline__ float fast_log(float x) {
  return __builtin_amdgcn_logf(x) * 0.6931471805599453f;
}

__global__ void k_flag(const void* mask, float* ws) {
  if (threadIdx.x == 0 && blockIdx.x == 0) {
    unsigned w = *(const unsigned*)mask;
    ((int*)(ws + OFF_FLAG))[0] = (w == 0x3F803F80u) ? 1 : 0;
  }
}

__global__ void k_prep(const void* wi, const void* wh, const void* gbi, const void* gbh,
                       const void* lcw, const void* lpw, const void* w1, const void* kb1,
                       const void* w2, const void* dw, const void* ddb, const void* aggw,
                       const void* pri, float* wsf, unsigned* U) {
  const int bf = ((const int*)(wsf + OFF_FLAG))[0];
  const int tid = blockIdx.x * blockDim.x + threadIdx.x;
  const int nT = gridDim.x * blockDim.x;
  // WHPK triples: x = (kp*512 + c)*3 + g ; src row = g*512+c, col 2kp
  for (int x = tid; x < 256 * 1536; x += nT) {
    int g = x % 3, y = x / 3, c = y % 512, kp = y / 512;
    long long r = (long long)(g * 512 + c) * Cn + 2 * kp;
    U[OFF_WHPK + x] = pack_h2(ld_any(wh, r, bf), ld_any(wh, r + 1, bf));
  }
  for (int x = tid; x < 256 * 512; x += nT) {
    int c = x % 512, kp = x / 512;
    long long r = (long long)c * Cn + 2 * kp;
    U[OFF_W1PK + x] = pack_h2(ld_any(w1, r, bf), ld_any(w1, r + 1, bf));
  }
  for (int x = tid; x < 256 * 168; x += nT) {
    int j = x % 168, kp = x / 168;
    long long r = (long long)j * Cn + 2 * kp;
    U[OFF_W2PK + x] = pack_h2(ld_any(w2, r, bf), ld_any(w2, r + 1, bf));
  }
  for (int x = tid; x < 40 * 1536; x += nT) {
    int g = x % 3, y = x / 3, c = y % 512, jp = y / 512;
    long long r = (long long)(g * 512 + c) * (In + Hn) + 2 * jp;
    U[OFF_WIFPK + x] = pack_h2(ld_any(wi, r, bf), ld_any(wi, r + 1, bf));
  }
  for (int x = tid; x < 256 * 1536; x += nT) {
    int g = x % 3, y = x / 3, c = y % 512, kp = y / 512;
    long long r = (long long)(g * 512 + c) * (In + Hn) + Hn + 2 * kp;
    U[OFF_WIPREVPK + x] = pack_h2(ld_any(wi, r, bf), ld_any(wi, r + 1, bf));
  }
  for (int x = tid; x < 512 * 1536; x += nT) {
    int i = x / 1536, m = x % 1536;
    wsf[OFF_WIPT + x] = ld_any(wi, (long long)m * (In + Hn) + Hn + i, bf);
  }
  for (int x = tid; x < G3; x += nT) wsf[OFF_BI + x] = ld_any(gbi, x, bf);
  for (int x = tid; x < G3; x += nT) wsf[OFF_BH + x] = ld_any(gbh, x, bf);
  for (int x = tid; x < Cn; x += nT) wsf[OFF_B1 + x] = ld_any(kb1, x, bf);
  for (int x = tid; x < LOCn * Kn; x += nT) wsf[OFF_LW + x] = ld_any(lcw, x, bf);
  for (int x = tid; x < 256 * LOCn; x += nT) wsf[OFF_PW + x] = ld_any(lpw, x, bf);
  for (int x = tid; x < 256 * LOCn; x += nT) wsf[OFF_DW + x] = ld_any(dw, x, bf);
  for (int x = tid; x < 256; x += nT) wsf[OFF_DB + x] = ld_any(ddb, x, bf);
  for (int x = tid; x < 256; x += nT) wsf[OFF_AGG + x] = ld_any(aggw, x, bf);
  for (int x = tid; x < Pn; x += nT) wsf[OFF_PRI + x] = ld_any(pri, x, bf);
}

// ENCW[b, sp, c, g] = pairs over s of sum_i enc[b,s,i] * wi[g*512+c, 80+i]
__global__ __launch_bounds__(1024) void k_encw(const void* __restrict__ enc_,
                                               const float* __restrict__ wsf,
                                               unsigned* __restrict__ U) {
  const int b = blockIdx.x >> 2, chunk = blockIdx.x & 3;
  const int bf = ((const int*)(wsf + OFF_FLAG))[0];
  const int tid = threadIdx.x;
  const int r = tid >> 8, m0 = tid & 255;
  const int s0 = chunk * 64 + r * 16;
  const float* WiPT = wsf + OFF_WIPT;
  for (int g6 = 0; g6 < 6; ++g6) {
    int m = m0 + (g6 << 8);
    float acc[16];
    #pragma unroll
    for (int j = 0; j < 16; ++j) acc[j] = 0.f;
    #pragma unroll 4
    for (int i = 0; i < In; ++i) {
      float w = WiPT[(size_t)i * G3 + m];
      #pragma unroll
      for (int j = 0; j < 16; ++j)
        acc[j] = fmaf(w, ld_any(enc_, ((long long)b * Sn + (s0 + j)) * In + i, bf), acc[j]);
    }
    int cc = m & 511, gg = m >> 9;
    unsigned* dst = U + OFF_ENCW + (size_t)b * 128 * G3;
    #pragma unroll
    for (int jj = 0; jj < 8; ++jj)
      dst[(size_t)(((s0 >> 1) + jj) * 512 + cc) * 3 + gg] = pack_h2(acc[2 * jj], acc[2 * jj + 1]);
  }
}

__global__ __launch_bounds__(1024) void k_aligner(
    const void* __restrict__ enc_, const void* __restrict__ mask_,
    const void* __restrict__ gt_, const float* __restrict__ wsf,
    const unsigned* __restrict__ U, void* __restrict__ out_, int use_encw) {
  const int b = blockIdx.x;
  const int tid = threadIdx.x;
  const int bf = ((const int*)(wsf + OFF_FLAG))[0];

  const float* BI = wsf + OFF_BI;
  const float* BH = wsf + OFF_BH;
  const float* B1 = wsf + OFF_B1;
  const float* lw = wsf + OFF_LW;
  const float* Pw = wsf + OFF_PW;
  const float* Dw = wsf + OFF_DW;
  const float* dbv = wsf + OFF_DB;
  const float* agg = wsf + OFF_AGG;
  const float* prw = wsf + OFF_PRI;

  __shared__ __align__(16) float sA[280];        // fp32 alpha padded at [10..265]
  __shared__ __align__(16) unsigned sAH[128];    // f16 alpha pairs
  __shared__ __align__(16) unsigned sXfH[40];    // f16 frame pairs
  __shared__ __align__(16) unsigned sPrevH[256]; // f16 context pairs (fallback)
  __shared__ __align__(16) float sHf[512];       // fp32 h
  __shared__ __align__(16) unsigned sHH[256];    // f16 h pairs
  __shared__ __align__(16) unsigned sT1H[256];   // f16 t1 pairs
  __shared__ __align__(16) float sXr[512], sXz[512], sXn[512];
  __shared__ __align__(16) float sHr[512], sHz[512], sHnM[512], sHnP[512];
  __shared__ __align__(16) float sDk[176];
  __shared__ __align__(16) float sFL[LOCn][Sn];
  __shared__ __align__(16) float sFD[LOCn][Sn];
  __shared__ __align__(16) float sPri[Sn];
  __shared__ __align__(16) float sMask[Sn];
  __shared__ __align__(16) float sR[1024];
  __shared__ float sRed2[8];

  for (int x = tid; x < 280; x += 1024) sA[x] = 0.f;
  for (int x = tid; x < 128; x += 1024) sAH[x] = 0u;
  for (int x = tid; x < Cn; x += 1024) sHf[x] = 0.f;
  for (int x = tid; x < 256; x += 1024) sHH[x] = 0u;
  for (int x = tid; x < Sn; x += 1024) sMask[x] = ld_any(mask_, (long long)b * Sn + x, bf);
  if (tid == 0) { sA[Kn / 2] = 1.f; sAH[0] = pack_h2(1.f, 0.f); }
  if (tid < Hn) ((_Float16*)sXfH)[tid] = (_Float16)ld_any(gt_, (long long)b * Tn * Hn + tid, bf);
  __syncthreads();

  const int Pp = use_encw ? 132 : 0;   // hn pairs moved to the gx half
  const int n3 = 256 - Pp;
  const int n1 = use_encw ? 128 : 256;
  const unsigned* encwB = U + OFF_ENCW + (size_t)b * 128 * G3;

  for (int t = 0; t < Tn; ++t) {
    // ---- S0 (fallback only): context = enc^T alpha, then pack f16 ----
    if (!use_encw) {
      int i = tid & (In - 1);
      int s0 = (tid >> 9) << 7;
      float acc = 0.f;
      if (bf) {
        const unsigned short* enc = (const unsigned short*)enc_ + (size_t)b * Sn * In + i;
        #pragma unroll 4
        for (int s = s0; s < s0 + 128; ++s)
          acc = fmaf(__uint_as_float(((unsigned)enc[(size_t)s * In]) << 16), sA[10 + s], acc);
      } else {
        const float* enc = (const float*)enc_ + (size_t)b * Sn * In + i;
        #pragma unroll 4
        for (int s = s0; s < s0 + 128; ++s)
          acc = fmaf(enc[(size_t)s * In], sA[10 + s], acc);
      }
      sR[tid] = acc;
      __syncthreads();
      if (tid < In) ((_Float16*)sPrevH)[tid] = (_Float16)(sR[tid] + sR[tid + In]);
      __syncthreads();
    }

    // ---- S1: big dots (f16 dot2) ----
    if (tid < Cn) {
      const int c = tid;
      float xr = BI[c], xz = BI[c + 512], xn = BI[c + 1024];
      {
        const unsigned* pf = U + OFF_WIFPK + 3 * c;
        #pragma unroll 4
        for (int jp = 0; jp < 40; ++jp) {
          unsigned a = sXfH[jp];
          xr = dot2f(pf[jp * G3], a, xr);
          xz = dot2f(pf[jp * G3 + 1], a, xz);
          xn = dot2f(pf[jp * G3 + 2], a, xn);
        }
      }
      {
        const unsigned* pm = use_encw ? (encwB + 3 * c) : (U + OFF_WIPREVPK + 3 * c);
        const unsigned* aSrc = use_encw ? sAH : sPrevH;
        #pragma unroll 4
        for (int kp = 0; kp < n1; ++kp) {
          unsigned a = aSrc[kp];
          xr = dot2f(pm[kp * G3], a, xr);
          xz = dot2f(pm[kp * G3 + 1], a, xz);
          xn = dot2f(pm[kp * G3 + 2], a, xn);
        }
      }
      {
        float hp = 0.f;
        const unsigned* ph = U + OFF_WHPK + 3 * c + 2;
        #pragma unroll 4
        for (int kp = n3; kp < 256; ++kp)
          hp = dot2f(ph[kp * G3], sHH[kp], hp);
        sHnP[c] = hp;
      }
      sXr[c] = xr; sXz[c] = xz; sXn[c] = xn;
    } else {
      const int c = tid - Cn;
      float hr = BH[c], hz = BH[c + 512], hn = BH[c + 1024];
      const unsigned* ph = U + OFF_WHPK + 3 * c;
      #pragma unroll 4
      for (int kp = 0; kp < n3; ++kp) {
        unsigned a = sHH[kp];
        hr = dot2f(ph[kp * G3], a, hr);
        hz = dot2f(ph[kp * G3 + 1], a, hz);
        hn = dot2f(ph[kp * G3 + 2], a, hn);
      }
      #pragma unroll 4
      for (int kp = n3; kp < 256; ++kp) {
        unsigned a = sHH[kp];
        hr = dot2f(ph[kp * G3], a, hr);
        hz = dot2f(ph[kp * G3 + 1], a, hz);
      }
      sHr[c] = hr; sHz[c] = hz; sHnM[c] = hn;
    }
    __syncthreads();

    // ---- S2: gates -> h (tid<512); loc conv + prior (tid>=512) ----
    if (tid < Cn) {
      int c = tid;
      float r = fast_sigmoid(sXr[c] + sHr[c]);
      float z = fast_sigmoid(sXz[c] + sHz[c]);
      float n = fast_tanh(sXn[c] + r * (sHnM[c] + sHnP[c]));
      float hN = (1.f - z) * n + z * sHf[c];
      sHf[c] = hN;
      ((_Float16*)sHH)[c] = (_Float16)hN;
    } else {
      int j = tid - Cn;
      #pragma unroll
      for (int rr = 0; rr < 4; ++rr) {
        int idx = j + (rr << 9);
        int l = idx >> 8, s = idx & (Sn - 1);
        float acc = 0.f;
        #pragma unroll
        for (int k = 0; k < Kn; ++k) acc = fmaf(lw[l * Kn + k], sA[s + k], acc);
        sFL[l][s] = acc;
      }
      if (j < Sn) {
        float acc = 0.f;
        #pragma unroll
        for (int k = 0; k < Pn; ++k) acc = fmaf(prw[k], sA[j + k], acc);
        sPri[j] = acc;
      }
    }
    __syncthreads();

    // ---- S3: t1 = tanh(W1 h + b1), split-k halves ----
    {
      int c = tid & (Cn - 1), half = tid >> 9;
      const unsigned* m1 = U + OFF_W1PK + half * 128 * 512 + c;
      float acc = 0.f;
      #pragma unroll 4
      for (int kp = 0; kp < 128; ++kp)
        acc = dot2f(m1[kp * 512], sHH[half * 128 + kp], acc);
      sR[tid] = acc;
    }
    __syncthreads();
    if (tid < Cn) ((_Float16*)sT1H)[tid] = (_Float16)fast_tanh(B1[tid] + sR[tid] + sR[tid + Cn]);
    __syncthreads();

    // ---- S4: dkern = W2 t1, split-k quarters ----
    if (tid < 672) {
      int kq = tid / 168, j = tid - kq * 168;
      const unsigned* m2 = U + OFF_W2PK + kq * 64 * 168 + j;
      float acc = 0.f;
      #pragma unroll 4
      for (int kp = 0; kp < 64; ++kp)
        acc = dot2f(m2[kp * 168], sT1H[kq * 64 + kp], acc);
      sR[tid] = acc;
    }
    __syncthreads();
    if (tid < LOCn * Kn) sDk[tid] = sR[tid] + sR[tid + 168] + sR[tid + 336] + sR[tid + 504];
    __syncthreads();

    // ---- S5: dynamic conv ----
    #pragma unroll
    for (int rr = 0; rr < 2; ++rr) {
      int idx = tid + (rr << 10);
      int l = idx >> 8, s = idx & (Sn - 1);
      float acc = 0.f;
      #pragma unroll
      for (int k = 0; k < Kn; ++k) acc = fmaf(sDk[l * Kn + k], sA[s + k], acc);
      sFD[l][s] = acc;
    }
    __syncthreads();

    // ---- S6: scorer partials (scalar weight loads via readfirstlane) ----
    {
      const int q = __builtin_amdgcn_readfirstlane(tid >> 8);
      const int s = tid & (Sn - 1);
      float fl0[LOCn], fd0[LOCn];
      #pragma unroll
      for (int l = 0; l < LOCn; ++l) { fl0[l] = sFL[l][s]; fd0[l] = sFD[l][s]; }
      float e = 0.f;
      const int c0 = q << 6;
      for (int c = c0; c < c0 + 64; ++c) {
        float sc = dbv[c];
        #pragma unroll
        for (int l = 0; l < LOCn; ++l) {
          sc = fmaf(Pw[c * LOCn + l], fl0[l], sc);
          sc = fmaf(Dw[c * LOCn + l], fd0[l], sc);
        }
        e = fmaf(agg[c], fast_tanh(sc), e);
      }
      sR[tid] = e;
    }
    __syncthreads();

    // ---- S7: energy + softmax + writes + frame prefetch ----
    float eVal = -__builtin_inff();
    if (tid < Sn) {
      eVal = sR[tid] + sR[tid + 256] + sR[tid + 512] + sR[tid + 768];
      eVal += fast_log(sPri[tid] + 1e-5f);
      if (!(sMask[tid] > 0.f)) eVal = -__builtin_inff();
      float m = eVal;
      #pragma unroll
      for (int off = 32; off > 0; off >>= 1) m = fmaxf(m, __shfl_xor(m, off, 64));
      if ((tid & 63) == 0) sRed2[tid >> 6] = m;
    }
    __syncthreads();
    float exv = 0.f;
    if (tid < Sn) {
      float M = fmaxf(fmaxf(sRed2[0], sRed2[1]), fmaxf(sRed2[2], sRed2[3]));
      exv = fast_exp(eVal - M);
      float ssum = exv;
      #pragma unroll
      for (int off = 32; off > 0; off >>= 1) ssum += __shfl_xor(ssum, off, 64);
      if ((tid & 63) == 0) sRed2[4 + (tid >> 6)] = ssum;
    }
    __syncthreads();
    if (tid < Sn) {
      float Z = sRed2[4] + sRed2[5] + sRed2[6] + sRed2[7];
      float a = exv * __builtin_amdgcn_rcpf(Z);
      sA[10 + tid] = a;
      ((_Float16*)sAH)[tid] = (_Float16)a;
      size_t oi = ((size_t)b * Tn + t) * Sn + tid;
      if (bf) ((__hip_bfloat16*)out_)[oi] = __float2bfloat16(a);
      else ((float*)out_)[oi] = a;
    } else if (tid >= 512 && tid < 512 + Hn && t + 1 < Tn) {
      int j = tid - 512;
      ((_Float16*)sXfH)[j] = (_Float16)ld_any(gt_, ((long long)b * Tn + t + 1) * Hn + j, bf);
    }
    __syncthreads();
  }
}

extern "C" void kernel_launch(void* const* d_in, const int* in_sizes, int n_in,
                              void* d_out, int out_size, void* d_ws, size_t ws_size,
                              hipStream_t stream) {
  float* wsf = (float*)d_ws;
  unsigned* U = (unsigned*)d_ws;
  const int use_encw = (ws_size >= (size_t)WS_END_ENCW * 4u) ? 1 : 0;
  k_flag<<<1, 64, 0, stream>>>(d_in[1], wsf);
  k_prep<<<1024, 256, 0, stream>>>(d_in[3], d_in[4], d_in[5], d_in[6],
                                   d_in[7], d_in[8], d_in[9], d_in[10],
                                   d_in[11], d_in[12], d_in[13], d_in[14],
                                   d_in[15], wsf, U);
  if (use_encw) k_encw<<<256, 1024, 0, stream>>>(d_in[0], wsf, U);
  k_aligner<<<Bn, 1024, 0, stream>>>(d_in[0], d_in[1], d_in[2], wsf, U, d_out, use_encw);
}

// Round 4
// 31185.843 us; speedup vs baseline: 2.5966x; 1.3533x over previous
//
#include <hip/hip_runtime.h>
#include <hip/hip_bf16.h>

#define Bn 64
#define Sn 256
#define In 512
#define Hn 80
#define Tn 600
#define Cn 512
#define LOCn 8
#define Kn 21
#define Pn 11
#define G3 1536

typedef _Float16 h2 __attribute__((ext_vector_type(2)));

// ---- ws layout (dword offsets) ----
enum : unsigned {
  OFF_WHPK     = 0u,                        // [256 kp][512 c][3 g] half2 pairs over h
  OFF_W1PK     = OFF_WHPK + 256u * 1536u,   // [256 kp][512 c]
  OFF_W2PK     = OFF_W1PK + 256u * 512u,    // [256 kp][168 j]
  OFF_WIFPK    = OFF_W2PK + 256u * 168u,    // [40 jp][512 c][3 g] frame part
  OFF_WIPREVPK = OFF_WIFPK + 40u * 1536u,   // [256 kp][512 c][3 g] prev part (fallback)
  OFF_BI       = OFF_WIPREVPK + 256u * 1536u,
  OFF_BH       = OFF_BI + 1536u,
  OFF_B1       = OFF_BH + 1536u,
  OFF_LW       = OFF_B1 + 512u,
  OFF_PW       = OFF_LW + 176u,
  OFF_DW       = OFF_PW + 2048u,
  OFF_DB       = OFF_DW + 2048u,
  OFF_AGG      = OFF_DB + 256u,
  OFF_PRI      = OFF_AGG + 256u,
  OFF_FLAG     = OFF_PRI + 16u,
  OFF_WIPT     = 1030400u,                  // fp32 [512 i][1536 m] = wi[m][80+i]
  OFF_ENCW     = OFF_WIPT + 512u * 1536u,   // [b][128 sp][512 c][3 g] half2 pairs over s
  WS_END_ENCW  = OFF_ENCW + 64u * 128u * 1536u,
  OFF_XH       = WS_END_ENCW,               // [64 grp][256] h f16 pairs
  OFF_XT1      = OFF_XH + 64u * 256u,       // [64 grp][256] t1 f16 pairs
  OFF_XE       = OFF_XT1 + 64u * 256u,      // [64 grp][256] energy f32 bits
  OFF_CTR      = OFF_XE + 64u * 256u,       // [64 grp][32] barrier counters
  WS_END_ALL   = OFF_CTR + 64u * 32u
};

__device__ __forceinline__ float ld_any(const void* p, long long i, int bf) {
  if (bf) {
    unsigned v = ((const unsigned short*)p)[i];
    return __uint_as_float(v << 16);
  }
  return ((const float*)p)[i];
}
__device__ __forceinline__ unsigned pack_h2(float a, float b) {
  union { h2 h; unsigned u; } x;
  x.h.x = (_Float16)a; x.h.y = (_Float16)b;
  return x.u;
}
__device__ __forceinline__ h2 u_to_h2(unsigned u) {
  union { h2 h; unsigned u; } x; x.u = u; return x.h;
}
__device__ __forceinline__ float dot2f(unsigned w, unsigned a, float acc) {
#if __has_builtin(__builtin_amdgcn_fdot2)
  return __builtin_amdgcn_fdot2(u_to_h2(w), u_to_h2(a), acc, false);
#else
  h2 wv = u_to_h2(w), av = u_to_h2(a);
  return fmaf((float)wv.x, (float)av.x, fmaf((float)wv.y, (float)av.y, acc));
#endif
}

__device__ __forceinline__ float fast_exp(float x) {
  return __builtin_amdgcn_exp2f(x * 1.4426950408889634f);
}
__device__ __forceinline__ float fast_sigmoid(float x) {
  return __builtin_amdgcn_rcpf(1.f + fast_exp(-x));
}
__device__ __forceinline__ float fast_tanh(float x) {
  float u = __builtin_amdgcn_exp2f(x * 2.8853900817779268f);
  return 1.f - 2.f * __builtin_amdgcn_rcpf(u + 1.f);
}
__device__ __forceinline__ float fast_log(float x) {
  return __builtin_amdgcn_logf(x) * 0.6931471805599453f;
}

__global__ void k_flag(const void* mask, float* ws) {
  if (threadIdx.x == 0 && blockIdx.x == 0) {
    unsigned w = *(const unsigned*)mask;
    ((int*)(ws + OFF_FLAG))[0] = (w == 0x3F803F80u) ? 1 : 0;
  }
}

__global__ void k_zero(unsigned* U) {
  int x = blockIdx.x * blockDim.x + threadIdx.x;
  if (x < 64 * 32) U[OFF_CTR + x] = 0u;
}

__global__ void k_prep(const void* wi, const void* wh, const void* gbi, const void* gbh,
                       const void* lcw, const void* lpw, const void* w1, const void* kb1,
                       const void* w2, const void* dw, const void* ddb, const void* aggw,
                       const void* pri, float* wsf, unsigned* U) {
  const int bf = ((const int*)(wsf + OFF_FLAG))[0];
  const int tid = blockIdx.x * blockDim.x + threadIdx.x;
  const int nT = gridDim.x * blockDim.x;
  for (int x = tid; x < 256 * 1536; x += nT) {
    int g = x % 3, y = x / 3, c = y % 512, kp = y / 512;
    long long r = (long long)(g * 512 + c) * Cn + 2 * kp;
    U[OFF_WHPK + x] = pack_h2(ld_any(wh, r, bf), ld_any(wh, r + 1, bf));
  }
  for (int x = tid; x < 256 * 512; x += nT) {
    int c = x % 512, kp = x / 512;
    long long r = (long long)c * Cn + 2 * kp;
    U[OFF_W1PK + x] = pack_h2(ld_any(w1, r, bf), ld_any(w1, r + 1, bf));
  }
  for (int x = tid; x < 256 * 168; x += nT) {
    int j = x % 168, kp = x / 168;
    long long r = (long long)j * Cn + 2 * kp;
    U[OFF_W2PK + x] = pack_h2(ld_any(w2, r, bf), ld_any(w2, r + 1, bf));
  }
  for (int x = tid; x < 40 * 1536; x += nT) {
    int g = x % 3, y = x / 3, c = y % 512, jp = y / 512;
    long long r = (long long)(g * 512 + c) * (In + Hn) + 2 * jp;
    U[OFF_WIFPK + x] = pack_h2(ld_any(wi, r, bf), ld_any(wi, r + 1, bf));
  }
  for (int x = tid; x < 256 * 1536; x += nT) {
    int g = x % 3, y = x / 3, c = y % 512, kp = y / 512;
    long long r = (long long)(g * 512 + c) * (In + Hn) + Hn + 2 * kp;
    U[OFF_WIPREVPK + x] = pack_h2(ld_any(wi, r, bf), ld_any(wi, r + 1, bf));
  }
  for (int x = tid; x < 512 * 1536; x += nT) {
    int i = x / 1536, m = x % 1536;
    wsf[OFF_WIPT + x] = ld_any(wi, (long long)m * (In + Hn) + Hn + i, bf);
  }
  for (int x = tid; x < G3; x += nT) wsf[OFF_BI + x] = ld_any(gbi, x, bf);
  for (int x = tid; x < G3; x += nT) wsf[OFF_BH + x] = ld_any(gbh, x, bf);
  for (int x = tid; x < Cn; x += nT) wsf[OFF_B1 + x] = ld_any(kb1, x, bf);
  for (int x = tid; x < LOCn * Kn; x += nT) wsf[OFF_LW + x] = ld_any(lcw, x, bf);
  for (int x = tid; x < 256 * LOCn; x += nT) wsf[OFF_PW + x] = ld_any(lpw, x, bf);
  for (int x = tid; x < 256 * LOCn; x += nT) wsf[OFF_DW + x] = ld_any(dw, x, bf);
  for (int x = tid; x < 256; x += nT) wsf[OFF_DB + x] = ld_any(ddb, x, bf);
  for (int x = tid; x < 256; x += nT) wsf[OFF_AGG + x] = ld_any(aggw, x, bf);
  for (int x = tid; x < Pn; x += nT) wsf[OFF_PRI + x] = ld_any(pri, x, bf);
}

__global__ __launch_bounds__(1024) void k_encw(const void* __restrict__ enc_,
                                               const float* __restrict__ wsf,
                                               unsigned* __restrict__ U) {
  const int b = blockIdx.x >> 2, chunk = blockIdx.x & 3;
  const int bf = ((const int*)(wsf + OFF_FLAG))[0];
  const int tid = threadIdx.x;
  const int r = tid >> 8, m0 = tid & 255;
  const int s0 = chunk * 64 + r * 16;
  const float* WiPT = wsf + OFF_WIPT;
  for (int g6 = 0; g6 < 6; ++g6) {
    int m = m0 + (g6 << 8);
    float acc[16];
    #pragma unroll
    for (int j = 0; j < 16; ++j) acc[j] = 0.f;
    #pragma unroll 4
    for (int i = 0; i < In; ++i) {
      float w = WiPT[(size_t)i * G3 + m];
      #pragma unroll
      for (int j = 0; j < 16; ++j)
        acc[j] = fmaf(w, ld_any(enc_, ((long long)b * Sn + (s0 + j)) * In + i, bf), acc[j]);
    }
    int cc = m & 511, gg = m >> 9;
    unsigned* dst = U + OFF_ENCW + (size_t)b * 128 * G3;
    #pragma unroll
    for (int jj = 0; jj < 8; ++jj)
      dst[(size_t)(((s0 >> 1) + jj) * 512 + cc) * 3 + gg] = pack_h2(acc[2 * jj], acc[2 * jj + 1]);
  }
}

// ---- group barrier: 4 blocks per group, monotonic epoch counter ----
__device__ __forceinline__ void gbar(unsigned* ctr, unsigned target) {
  __syncthreads();
  if (threadIdx.x == 0) {
    __threadfence();
    __hip_atomic_fetch_add(ctr, 1u, __ATOMIC_RELEASE, __HIP_MEMORY_SCOPE_AGENT);
    while (__hip_atomic_load(ctr, __ATOMIC_ACQUIRE, __HIP_MEMORY_SCOPE_AGENT) < target) {
      __builtin_amdgcn_s_sleep(8);
    }
  }
  __syncthreads();
}

// ---- 4-way split kernel: 4 blocks per batch row ----
__global__ __launch_bounds__(1024, 4) void k_split(
    const void* __restrict__ mask_, const void* __restrict__ gt_,
    const float* __restrict__ wsf, unsigned* __restrict__ UW,
    void* __restrict__ out_) {
  const int b = blockIdx.x >> 2;
  const int j = blockIdx.x & 3;
  const int tid = threadIdx.x;
  const int bf = ((const int*)(wsf + OFF_FLAG))[0];

  const float* BI = wsf + OFF_BI;
  const float* BH = wsf + OFF_BH;
  const float* B1 = wsf + OFF_B1;
  const float* lw = wsf + OFF_LW;
  const float* Pw = wsf + OFF_PW;
  const float* Dw = wsf + OFF_DW;
  const float* dbv = wsf + OFF_DB;
  const float* agg = wsf + OFF_AGG;
  const float* prw = wsf + OFF_PRI;
  const unsigned* U = UW;
  const unsigned* encwB = U + OFF_ENCW + (size_t)b * 128 * G3;
  unsigned* ctr = UW + OFF_CTR + b * 32;

  __shared__ __align__(16) float sA[280];
  __shared__ __align__(16) unsigned sAH[128];
  __shared__ __align__(16) unsigned sXfH[40];
  __shared__ __align__(16) unsigned sHH[256];
  __shared__ __align__(16) unsigned sT1H[256];
  __shared__ __align__(16) float sHfC[128];
  __shared__ __align__(16) float sHn[128];
  __shared__ __align__(16) float sP[6 * 8 * 128];
  __shared__ __align__(16) float sG6[768];
  __shared__ __align__(16) float sFLo[8 * 64];
  __shared__ __align__(16) float sFDo[8 * 64];
  __shared__ __align__(16) float sPriL[64];
  __shared__ __align__(16) float sDk[176];
  __shared__ __align__(16) float sMask[256];
  __shared__ float sRed2[8];

  for (int x = tid; x < 280; x += 1024) sA[x] = 0.f;
  for (int x = tid; x < 128; x += 1024) { sAH[x] = 0u; sHfC[x] = 0.f; }
  for (int x = tid; x < 256; x += 1024) { sHH[x] = 0u;
    sMask[x] = ld_any(mask_, (long long)b * Sn + x, bf); }
  if (tid == 0) { sA[10] = 1.f; sAH[0] = pack_h2(1.f, 0.f); }
  if (tid < 40) sXfH[tid] = pack_h2(ld_any(gt_, (long long)b * Tn * Hn + 2 * tid, bf),
                                    ld_any(gt_, (long long)b * Tn * Hn + 2 * tid + 1, bf));
  __syncthreads();

  for (int t = 0; t < Tn; ++t) {
    // ---- S1: gate dots, c-range [128j,128j+128), 8-way split-k ----
    {
      const int ks = tid >> 7, cl = tid & 127;
      const int c = (j << 7) + cl;
      float xr = 0.f, xz = 0.f, xn = 0.f, hr = 0.f, hz = 0.f, hn = 0.f;
      const unsigned* pf = U + OFF_WIFPK + 3 * c;
      #pragma unroll
      for (int jp = ks * 5; jp < ks * 5 + 5; ++jp) {
        unsigned a = sXfH[jp];
        xr = dot2f(pf[jp * G3], a, xr);
        xz = dot2f(pf[jp * G3 + 1], a, xz);
        xn = dot2f(pf[jp * G3 + 2], a, xn);
      }
      const unsigned* pe = encwB + 3 * c;
      #pragma unroll 4
      for (int kp = ks * 16; kp < ks * 16 + 16; ++kp) {
        unsigned a = sAH[kp];
        xr = dot2f(pe[kp * G3], a, xr);
        xz = dot2f(pe[kp * G3 + 1], a, xz);
        xn = dot2f(pe[kp * G3 + 2], a, xn);
      }
      const unsigned* ph = U + OFF_WHPK + 3 * c;
      #pragma unroll 4
      for (int kp = ks * 32; kp < ks * 32 + 32; ++kp) {
        unsigned a = sHH[kp];
        hr = dot2f(ph[kp * G3], a, hr);
        hz = dot2f(ph[kp * G3 + 1], a, hz);
        hn = dot2f(ph[kp * G3 + 2], a, hn);
      }
      sP[(0 * 8 + ks) * 128 + cl] = xr;
      sP[(1 * 8 + ks) * 128 + cl] = xz;
      sP[(2 * 8 + ks) * 128 + cl] = xn;
      sP[(3 * 8 + ks) * 128 + cl] = hr;
      sP[(4 * 8 + ks) * 128 + cl] = hz;
      sP[(5 * 8 + ks) * 128 + cl] = hn;
    }
    __syncthreads();
    if (tid < 768) {
      int g = tid >> 7, cl = tid & 127;
      float s = 0.f;
      #pragma unroll
      for (int ks = 0; ks < 8; ++ks) s += sP[(g * 8 + ks) * 128 + cl];
      sG6[tid] = s;
    }
    __syncthreads();
    // gates (tid<128) | prior conv (192..255) | loc conv (512..1023)
    if (tid < 128) {
      int cl = tid, c = (j << 7) + cl;
      float xr = sG6[cl] + BI[c];
      float xz = sG6[128 + cl] + BI[512 + c];
      float xn = sG6[256 + cl] + BI[1024 + c];
      float hr = sG6[384 + cl] + BH[c];
      float hz = sG6[512 + cl] + BH[512 + c];
      float hn = sG6[640 + cl] + BH[1024 + c];
      float r = fast_sigmoid(xr + hr);
      float z = fast_sigmoid(xz + hz);
      float n = fast_tanh(xn + r * hn);
      float hN = (1.f - z) * n + z * sHfC[cl];
      sHfC[cl] = hN; sHn[cl] = hN;
    } else if (tid >= 192 && tid < 256) {
      int sl = tid - 192;
      float acc = 0.f;
      #pragma unroll
      for (int k = 0; k < Pn; ++k) acc = fmaf(prw[k], sA[(j << 6) + sl + k], acc);
      sPriL[sl] = acc;
    } else if (tid >= 512) {
      int idx = tid - 512;
      int l = __builtin_amdgcn_readfirstlane(idx >> 6), sl = idx & 63;
      float acc = 0.f;
      #pragma unroll
      for (int k = 0; k < Kn; ++k) acc = fmaf(lw[l * Kn + k], sA[(j << 6) + sl + k], acc);
      sFLo[l * 64 + sl] = acc;
    }
    __syncthreads();
    if (tid < 64) UW[OFF_XH + b * 256 + (j << 6) + tid] = pack_h2(sHn[2 * tid], sHn[2 * tid + 1]);
    gbar(ctr, 12u * t + 4u);
    if (tid < 256)
      sHH[tid] = __hip_atomic_load(&UW[OFF_XH + b * 256 + tid], __ATOMIC_RELAXED, __HIP_MEMORY_SCOPE_AGENT);
    __syncthreads();

    // ---- S3: t1 chunk = tanh(W1 h + b1), 8-way split-k ----
    {
      const int ks = tid >> 7, cl = tid & 127;
      const int c = (j << 7) + cl;
      const unsigned* m1 = U + OFF_W1PK + c;
      float acc = 0.f;
      #pragma unroll 4
      for (int kp = ks * 32; kp < ks * 32 + 32; ++kp)
        acc = dot2f(m1[kp * 512], sHH[kp], acc);
      sP[ks * 128 + cl] = acc;
    }
    __syncthreads();
    if (tid < 128) {
      float a = B1[(j << 7) + tid];
      #pragma unroll
      for (int ks = 0; ks < 8; ++ks) a += sP[ks * 128 + tid];
      sHn[tid] = fast_tanh(a);
    }
    __syncthreads();
    if (tid < 64) UW[OFF_XT1 + b * 256 + (j << 6) + tid] = pack_h2(sHn[2 * tid], sHn[2 * tid + 1]);
    gbar(ctr, 12u * t + 8u);
    if (tid < 256)
      sT1H[tid] = __hip_atomic_load(&UW[OFF_XT1 + b * 256 + tid], __ATOMIC_RELAXED, __HIP_MEMORY_SCOPE_AGENT);
    __syncthreads();

    // ---- S4: dkern = W2 t1 (replicated, split-k quarters) ----
    if (tid < 672) {
      int kq = tid / 168, j2 = tid - kq * 168;
      const unsigned* m2 = U + OFF_W2PK + kq * 64 * 168 + j2;
      float acc = 0.f;
      #pragma unroll 4
      for (int kp = 0; kp < 64; ++kp)
        acc = dot2f(m2[kp * 168], sT1H[kq * 64 + kp], acc);
      sP[tid] = acc;
    }
    __syncthreads();
    if (tid < 168) sDk[tid] = sP[tid] + sP[tid + 168] + sP[tid + 336] + sP[tid + 504];
    __syncthreads();

    // ---- S5: dynamic conv for own s-range ----
    if (tid < 512) {
      int l = __builtin_amdgcn_readfirstlane(tid >> 6), sl = tid & 63;
      float acc = 0.f;
      #pragma unroll
      for (int k = 0; k < Kn; ++k) acc = fmaf(sDk[l * Kn + k], sA[(j << 6) + sl + k], acc);
      sFDo[l * 64 + sl] = acc;
    }
    __syncthreads();

    // ---- S6: scorer partials, 16 c-slices x 64 s ----
    {
      const int sl = tid & 63;
      const int slice = __builtin_amdgcn_readfirstlane(tid >> 6);
      float fl[LOCn], fd[LOCn];
      #pragma unroll
      for (int l = 0; l < LOCn; ++l) { fl[l] = sFLo[l * 64 + sl]; fd[l] = sFDo[l * 64 + sl]; }
      float e = 0.f;
      const int c0 = slice << 4;
      for (int c = c0; c < c0 + 16; ++c) {
        float sc = dbv[c];
        #pragma unroll
        for (int l = 0; l < LOCn; ++l) {
          sc = fmaf(Pw[c * LOCn + l], fl[l], sc);
          sc = fmaf(Dw[c * LOCn + l], fd[l], sc);
        }
        e = fmaf(agg[c], fast_tanh(sc), e);
      }
      sP[slice * 64 + sl] = e;
    }
    __syncthreads();
    if (tid < 64) {
      float E = 0.f;
      #pragma unroll
      for (int q = 0; q < 16; ++q) E += sP[q * 64 + tid];
      E += fast_log(sPriL[tid] + 1e-5f);
      if (!(sMask[(j << 6) + tid] > 0.f)) E = -__builtin_inff();
      UW[OFF_XE + b * 256 + (j << 6) + tid] = __float_as_uint(E);
    }
    gbar(ctr, 12u * t + 12u);

    // ---- S7: softmax (replicated) + alpha + output ----
    float eV = -__builtin_inff(), exv = 0.f;
    if (tid < 256) {
      eV = __uint_as_float(
          __hip_atomic_load(&UW[OFF_XE + b * 256 + tid], __ATOMIC_RELAXED, __HIP_MEMORY_SCOPE_AGENT));
      float m = eV;
      #pragma unroll
      for (int off = 32; off > 0; off >>= 1) m = fmaxf(m, __shfl_xor(m, off, 64));
      if ((tid & 63) == 0) sRed2[tid >> 6] = m;
    }
    __syncthreads();
    if (tid < 256) {
      float M = fmaxf(fmaxf(sRed2[0], sRed2[1]), fmaxf(sRed2[2], sRed2[3]));
      exv = fast_exp(eV - M);
      float ssum = exv;
      #pragma unroll
      for (int off = 32; off > 0; off >>= 1) ssum += __shfl_xor(ssum, off, 64);
      if ((tid & 63) == 0) sRed2[4 + (tid >> 6)] = ssum;
    } else if (tid >= 512 && tid < 552 && t + 1 < Tn) {
      int i = tid - 512;
      sXfH[i] = pack_h2(ld_any(gt_, ((long long)b * Tn + t + 1) * Hn + 2 * i, bf),
                        ld_any(gt_, ((long long)b * Tn + t + 1) * Hn + 2 * i + 1, bf));
    }
    __syncthreads();
    if (tid < 256) {
      float Z = sRed2[4] + sRed2[5] + sRed2[6] + sRed2[7];
      sA[10 + tid] = exv * __builtin_amdgcn_rcpf(Z);
    }
    __syncthreads();
    if (tid < 128) sAH[tid] = pack_h2(sA[10 + 2 * tid], sA[10 + 2 * tid + 1]);
    else if (tid >= 256 && tid < 320) {
      int s = (j << 6) + (tid - 256);
      float a = sA[10 + s];
      size_t oi = ((size_t)b * Tn + t) * Sn + s;
      if (bf) ((__hip_bfloat16*)out_)[oi] = __float2bfloat16(a);
      else ((float*)out_)[oi] = a;
    }
    __syncthreads();
  }
}

// ---- fallback: R3 single-block-per-batch kernel ----
__global__ __launch_bounds__(1024) void k_single(
    const void* __restrict__ enc_, const void* __restrict__ mask_,
    const void* __restrict__ gt_, const float* __restrict__ wsf,
    const unsigned* __restrict__ U, void* __restrict__ out_, int use_encw) {
  const int b = blockIdx.x;
  const int tid = threadIdx.x;
  const int bf = ((const int*)(wsf + OFF_FLAG))[0];
  const float* BI = wsf + OFF_BI;
  const float* BH = wsf + OFF_BH;
  const float* B1 = wsf + OFF_B1;
  const float* lw = wsf + OFF_LW;
  const float* Pw = wsf + OFF_PW;
  const float* Dw = wsf + OFF_DW;
  const float* dbv = wsf + OFF_DB;
  const float* agg = wsf + OFF_AGG;
  const float* prw = wsf + OFF_PRI;

  __shared__ __align__(16) float sA[280];
  __shared__ __align__(16) unsigned sAH[128];
  __shared__ __align__(16) unsigned sXfH[40];
  __shared__ __align__(16) unsigned sPrevH[256];
  __shared__ __align__(16) float sHf[512];
  __shared__ __align__(16) unsigned sHH[256];
  __shared__ __align__(16) unsigned sT1H[256];
  __shared__ __align__(16) float sXr[512], sXz[512], sXn[512];
  __shared__ __align__(16) float sHr[512], sHz[512], sHnM[512], sHnP[512];
  __shared__ __align__(16) float sDk[176];
  __shared__ __align__(16) float sFL[LOCn][Sn];
  __shared__ __align__(16) float sFD[LOCn][Sn];
  __shared__ __align__(16) float sPri[Sn];
  __shared__ __align__(16) float sMask[Sn];
  __shared__ __align__(16) float sR[1024];
  __shared__ float sRed2[8];

  for (int x = tid; x < 280; x += 1024) sA[x] = 0.f;
  for (int x = tid; x < 128; x += 1024) sAH[x] = 0u;
  for (int x = tid; x < Cn; x += 1024) sHf[x] = 0.f;
  for (int x = tid; x < 256; x += 1024) sHH[x] = 0u;
  for (int x = tid; x < Sn; x += 1024) sMask[x] = ld_any(mask_, (long long)b * Sn + x, bf);
  if (tid == 0) { sA[Kn / 2] = 1.f; sAH[0] = pack_h2(1.f, 0.f); }
  if (tid < Hn) ((_Float16*)sXfH)[tid] = (_Float16)ld_any(gt_, (long long)b * Tn * Hn + tid, bf);
  __syncthreads();

  const int Pp = use_encw ? 132 : 0;
  const int n3 = 256 - Pp;
  const int n1 = use_encw ? 128 : 256;
  const unsigned* encwB = U + OFF_ENCW + (size_t)b * 128 * G3;

  for (int t = 0; t < Tn; ++t) {
    if (!use_encw) {
      int i = tid & (In - 1);
      int s0 = (tid >> 9) << 7;
      float acc = 0.f;
      if (bf) {
        const unsigned short* enc = (const unsigned short*)enc_ + (size_t)b * Sn * In + i;
        #pragma unroll 4
        for (int s = s0; s < s0 + 128; ++s)
          acc = fmaf(__uint_as_float(((unsigned)enc[(size_t)s * In]) << 16), sA[10 + s], acc);
      } else {
        const float* enc = (const float*)enc_ + (size_t)b * Sn * In + i;
        #pragma unroll 4
        for (int s = s0; s < s0 + 128; ++s)
          acc = fmaf(enc[(size_t)s * In], sA[10 + s], acc);
      }
      sR[tid] = acc;
      __syncthreads();
      if (tid < In) ((_Float16*)sPrevH)[tid] = (_Float16)(sR[tid] + sR[tid + In]);
      __syncthreads();
    }
    if (tid < Cn) {
      const int c = tid;
      float xr = BI[c], xz = BI[c + 512], xn = BI[c + 1024];
      {
        const unsigned* pf = U + OFF_WIFPK + 3 * c;
        #pragma unroll 4
        for (int jp = 0; jp < 40; ++jp) {
          unsigned a = sXfH[jp];
          xr = dot2f(pf[jp * G3], a, xr);
          xz = dot2f(pf[jp * G3 + 1], a, xz);
          xn = dot2f(pf[jp * G3 + 2], a, xn);
        }
      }
      {
        const unsigned* pm = use_encw ? (encwB + 3 * c) : (U + OFF_WIPREVPK + 3 * c);
        const unsigned* aSrc = use_encw ? sAH : sPrevH;
        #pragma unroll 4
        for (int kp = 0; kp < n1; ++kp) {
          unsigned a = aSrc[kp];
          xr = dot2f(pm[kp * G3], a, xr);
          xz = dot2f(pm[kp * G3 + 1], a, xz);
          xn = dot2f(pm[kp * G3 + 2], a, xn);
        }
      }
      {
        float hp = 0.f;
        const unsigned* ph = U + OFF_WHPK + 3 * c + 2;
        #pragma unroll 4
        for (int kp = n3; kp < 256; ++kp)
          hp = dot2f(ph[kp * G3], sHH[kp], hp);
        sHnP[c] = hp;
      }
      sXr[c] = xr; sXz[c] = xz; sXn[c] = xn;
    } else {
      const int c = tid - Cn;
      float hr = BH[c], hz = BH[c + 512], hn = BH[c + 1024];
      const unsigned* ph = U + OFF_WHPK + 3 * c;
      #pragma unroll 4
      for (int kp = 0; kp < n3; ++kp) {
        unsigned a = sHH[kp];
        hr = dot2f(ph[kp * G3], a, hr);
        hz = dot2f(ph[kp * G3 + 1], a, hz);
        hn = dot2f(ph[kp * G3 + 2], a, hn);
      }
      #pragma unroll 4
      for (int kp = n3; kp < 256; ++kp) {
        unsigned a = sHH[kp];
        hr = dot2f(ph[kp * G3], a, hr);
        hz = dot2f(ph[kp * G3 + 1], a, hz);
      }
      sHr[c] = hr; sHz[c] = hz; sHnM[c] = hn;
    }
    __syncthreads();
    if (tid < Cn) {
      int c = tid;
      float r = fast_sigmoid(sXr[c] + sHr[c]);
      float z = fast_sigmoid(sXz[c] + sHz[c]);
      float n = fast_tanh(sXn[c] + r * (sHnM[c] + sHnP[c]));
      float hN = (1.f - z) * n + z * sHf[c];
      sHf[c] = hN;
      ((_Float16*)sHH)[c] = (_Float16)hN;
    } else {
      int j = tid - Cn;
      #pragma unroll
      for (int rr = 0; rr < 4; ++rr) {
        int idx = j + (rr << 9);
        int l = idx >> 8, s = idx & (Sn - 1);
        float acc = 0.f;
        #pragma unroll
        for (int k = 0; k < Kn; ++k) acc = fmaf(lw[l * Kn + k], sA[s + k], acc);
        sFL[l][s] = acc;
      }
      if (j < Sn) {
        float acc = 0.f;
        #pragma unroll
        for (int k = 0; k < Pn; ++k) acc = fmaf(prw[k], sA[j + k], acc);
        sPri[j] = acc;
      }
    }
    __syncthreads();
    {
      int c = tid & (Cn - 1), half = tid >> 9;
      const unsigned* m1 = U + OFF_W1PK + half * 128 * 512 + c;
      float acc = 0.f;
      #pragma unroll 4
      for (int kp = 0; kp < 128; ++kp)
        acc = dot2f(m1[kp * 512], sHH[half * 128 + kp], acc);
      sR[tid] = acc;
    }
    __syncthreads();
    if (tid < Cn) ((_Float16*)sT1H)[tid] = (_Float16)fast_tanh(B1[tid] + sR[tid] + sR[tid + Cn]);
    __syncthreads();
    if (tid < 672) {
      int kq = tid / 168, j = tid - kq * 168;
      const unsigned* m2 = U + OFF_W2PK + kq * 64 * 168 + j;
      float acc = 0.f;
      #pragma unroll 4
      for (int kp = 0; kp < 64; ++kp)
        acc = dot2f(m2[kp * 168], sT1H[kq * 64 + kp], acc);
      sR[tid] = acc;
    }
    __syncthreads();
    if (tid < LOCn * Kn) sDk[tid] = sR[tid] + sR[tid + 168] + sR[tid + 336] + sR[tid + 504];
    __syncthreads();
    #pragma unroll
    for (int rr = 0; rr < 2; ++rr) {
      int idx = tid + (rr << 10);
      int l = idx >> 8, s = idx & (Sn - 1);
      float acc = 0.f;
      #pragma unroll
      for (int k = 0; k < Kn; ++k) acc = fmaf(sDk[l * Kn + k], sA[s + k], acc);
      sFD[l][s] = acc;
    }
    __syncthreads();
    {
      const int q = __builtin_amdgcn_readfirstlane(tid >> 8);
      const int s = tid & (Sn - 1);
      float fl0[LOCn], fd0[LOCn];
      #pragma unroll
      for (int l = 0; l < LOCn; ++l) { fl0[l] = sFL[l][s]; fd0[l] = sFD[l][s]; }
      float e = 0.f;
      const int c0 = q << 6;
      for (int c = c0; c < c0 + 64; ++c) {
        float sc = dbv[c];
        #pragma unroll
        for (int l = 0; l < LOCn; ++l) {
          sc = fmaf(Pw[c * LOCn + l], fl0[l], sc);
          sc = fmaf(Dw[c * LOCn + l], fd0[l], sc);
        }
        e = fmaf(agg[c], fast_tanh(sc), e);
      }
      sR[tid] = e;
    }
    __syncthreads();
    float eVal = -__builtin_inff();
    if (tid < Sn) {
      eVal = sR[tid] + sR[tid + 256] + sR[tid + 512] + sR[tid + 768];
      eVal += fast_log(sPri[tid] + 1e-5f);
      if (!(sMask[tid] > 0.f)) eVal = -__builtin_inff();
      float m = eVal;
      #pragma unroll
      for (int off = 32; off > 0; off >>= 1) m = fmaxf(m, __shfl_xor(m, off, 64));
      if ((tid & 63) == 0) sRed2[tid >> 6] = m;
    }
    __syncthreads();
    float exv = 0.f;
    if (tid < Sn) {
      float M = fmaxf(fmaxf(sRed2[0], sRed2[1]), fmaxf(sRed2[2], sRed2[3]));
      exv = fast_exp(eVal - M);
      float ssum = exv;
      #pragma unroll
      for (int off = 32; off > 0; off >>= 1) ssum += __shfl_xor(ssum, off, 64);
      if ((tid & 63) == 0) sRed2[4 + (tid >> 6)] = ssum;
    }
    __syncthreads();
    if (tid < Sn) {
      float Z = sRed2[4] + sRed2[5] + sRed2[6] + sRed2[7];
      float a = exv * __builtin_amdgcn_rcpf(Z);
      sA[10 + tid] = a;
      ((_Float16*)sAH)[tid] = (_Float16)a;
      size_t oi = ((size_t)b * Tn + t) * Sn + tid;
      if (bf) ((__hip_bfloat16*)out_)[oi] = __float2bfloat16(a);
      else ((float*)out_)[oi] = a;
    } else if (tid >= 512 && tid < 512 + Hn && t + 1 < Tn) {
      int j = tid - 512;
      ((_Float16*)sXfH)[j] = (_Float16)ld_any(gt_, ((long long)b * Tn + t + 1) * Hn + j, bf);
    }
    __syncthreads();
  }
}

extern "C" void kernel_launch(void* const* d_in, const int* in_sizes, int n_in,
                              void* d_out, int out_size, void* d_ws, size_t ws_size,
                              hipStream_t stream) {
  float* wsf = (float*)d_ws;
  unsigned* U = (unsigned*)d_ws;
  const int use_encw = (ws_size >= (size_t)WS_END_ENCW * 4u) ? 1 : 0;
  const int use_split = (ws_size >= (size_t)WS_END_ALL * 4u) ? 1 : 0;
  k_flag<<<1, 64, 0, stream>>>(d_in[1], wsf);
  k_prep<<<1024, 256, 0, stream>>>(d_in[3], d_in[4], d_in[5], d_in[6],
                                   d_in[7], d_in[8], d_in[9], d_in[10],
                                   d_in[11], d_in[12], d_in[13], d_in[14],
                                   d_in[15], wsf, U);
  if (use_split) {
    k_encw<<<256, 1024, 0, stream>>>(d_in[0], wsf, U);
    k_zero<<<8, 256, 0, stream>>>(U);
    k_split<<<256, 1024, 0, stream>>>(d_in[1], d_in[2], wsf, U, d_out);
  } else {
    if (use_encw) k_encw<<<256, 1024, 0, stream>>>(d_in[0], wsf, U);
    k_single<<<Bn, 1024, 0, stream>>>(d_in[0], d_in[1], d_in[2], wsf, U, d_out, use_encw);
  }
}

// Round 5
// 18706.245 us; speedup vs baseline: 4.3288x; 1.6671x over previous
//
#include <hip/hip_runtime.h>
#include <hip/hip_bf16.h>

#define Bn 64
#define Sn 256
#define In 512
#define Hn 80
#define Tn 600
#define Cn 512
#define LOCn 8
#define Kn 21
#define Pn 11
#define G3 1536

typedef _Float16 h2 __attribute__((ext_vector_type(2)));

// ---- ws layout (dword offsets) ----
enum : unsigned {
  OFF_WHPK     = 0u,                        // [256 kp][512 c][3 g] half2 pairs over h
  OFF_W1PK     = OFF_WHPK + 256u * 1536u,   // [256 kp][512 c]
  OFF_W2PK     = OFF_W1PK + 256u * 512u,    // [256 kp][168 j]
  OFF_WIFPK    = OFF_W2PK + 256u * 168u,    // [40 jp][512 c][3 g] frame part
  OFF_WIPREVPK = OFF_WIFPK + 40u * 1536u,   // [256 kp][512 c][3 g] prev part (fallback)
  OFF_BI       = OFF_WIPREVPK + 256u * 1536u,
  OFF_BH       = OFF_BI + 1536u,
  OFF_B1       = OFF_BH + 1536u,
  OFF_LW       = OFF_B1 + 512u,
  OFF_PW       = OFF_LW + 176u,
  OFF_DW       = OFF_PW + 2048u,
  OFF_DB       = OFF_DW + 2048u,
  OFF_AGG      = OFF_DB + 256u,
  OFF_PRI      = OFF_AGG + 256u,
  OFF_FLAG     = OFF_PRI + 16u,
  OFF_WIPT     = 1030400u,                  // fp32 [512 i][1536 m] = wi[m][80+i]
  OFF_ENCW     = OFF_WIPT + 512u * 1536u,   // [b][128 sp][512 c][3 g] half2 pairs over s
  WS_END_ENCW  = OFF_ENCW + 64u * 128u * 1536u,
  OFF_XH       = WS_END_ENCW,               // [64][256] full-h f16 pairs
  OFF_TP       = OFF_XH + 64u * 256u,       // [64][8][512] t1 partials f32
  OFF_XE       = OFF_TP + 64u * 4096u,      // [64][256] energy f32 bits
  OFF_FLG      = OFF_XE + 64u * 256u,       // [64][32]: A at +0..3, B at +16..19
  WS_END_ALL   = OFF_FLG + 64u * 32u
};

__device__ __forceinline__ float ld_any(const void* p, long long i, int bf) {
  if (bf) {
    unsigned v = ((const unsigned short*)p)[i];
    return __uint_as_float(v << 16);
  }
  return ((const float*)p)[i];
}
__device__ __forceinline__ unsigned pack_h2(float a, float b) {
  union { h2 h; unsigned u; } x;
  x.h.x = (_Float16)a; x.h.y = (_Float16)b;
  return x.u;
}
__device__ __forceinline__ h2 u_to_h2(unsigned u) {
  union { h2 h; unsigned u; } x; x.u = u; return x.h;
}
__device__ __forceinline__ float dot2f(unsigned w, unsigned a, float acc) {
#if __has_builtin(__builtin_amdgcn_fdot2)
  return __builtin_amdgcn_fdot2(u_to_h2(w), u_to_h2(a), acc, false);
#else
  h2 wv = u_to_h2(w), av = u_to_h2(a);
  return fmaf((float)wv.x, (float)av.x, fmaf((float)wv.y, (float)av.y, acc));
#endif
}

// fine-grained device-coherent ops: sc1 path, NO cache-wide wb/inv
__device__ __forceinline__ void st_dev(unsigned* p, unsigned v) {
  __hip_atomic_store(p, v, __ATOMIC_RELAXED, __HIP_MEMORY_SCOPE_AGENT);
}
__device__ __forceinline__ unsigned ld_dev(const unsigned* p) {
  return __hip_atomic_load(p, __ATOMIC_RELAXED, __HIP_MEMORY_SCOPE_AGENT);
}

__device__ __forceinline__ float fast_exp(float x) {
  return __builtin_amdgcn_exp2f(x * 1.4426950408889634f);
}
__device__ __forceinline__ float fast_sigmoid(float x) {
  return __builtin_amdgcn_rcpf(1.f + fast_exp(-x));
}
__device__ __forceinline__ float fast_tanh(float x) {
  float u = __builtin_amdgcn_exp2f(x * 2.8853900817779268f);
  return 1.f - 2.f * __builtin_amdgcn_rcpf(u + 1.f);
}
__device__ __forceinline__ float fast_log(float x) {
  return __builtin_amdgcn_logf(x) * 0.6931471805599453f;
}

__global__ void k_flag(const void* mask, float* ws) {
  if (threadIdx.x == 0 && blockIdx.x == 0) {
    unsigned w = *(const unsigned*)mask;
    ((int*)(ws + OFF_FLAG))[0] = (w == 0x3F803F80u) ? 1 : 0;
  }
}

__global__ void k_zero(unsigned* U) {
  int x = blockIdx.x * blockDim.x + threadIdx.x;
  if (x < 64 * 32) U[OFF_FLG + x] = 0u;
}

__global__ void k_prep(const void* wi, const void* wh, const void* gbi, const void* gbh,
                       const void* lcw, const void* lpw, const void* w1, const void* kb1,
                       const void* w2, const void* dw, const void* ddb, const void* aggw,
                       const void* pri, float* wsf, unsigned* U) {
  const int bf = ((const int*)(wsf + OFF_FLAG))[0];
  const int tid = blockIdx.x * blockDim.x + threadIdx.x;
  const int nT = gridDim.x * blockDim.x;
  for (int x = tid; x < 256 * 1536; x += nT) {
    int g = x % 3, y = x / 3, c = y % 512, kp = y / 512;
    long long r = (long long)(g * 512 + c) * Cn + 2 * kp;
    U[OFF_WHPK + x] = pack_h2(ld_any(wh, r, bf), ld_any(wh, r + 1, bf));
  }
  for (int x = tid; x < 256 * 512; x += nT) {
    int c = x % 512, kp = x / 512;
    long long r = (long long)c * Cn + 2 * kp;
    U[OFF_W1PK + x] = pack_h2(ld_any(w1, r, bf), ld_any(w1, r + 1, bf));
  }
  for (int x = tid; x < 256 * 168; x += nT) {
    int j = x % 168, kp = x / 168;
    long long r = (long long)j * Cn + 2 * kp;
    U[OFF_W2PK + x] = pack_h2(ld_any(w2, r, bf), ld_any(w2, r + 1, bf));
  }
  for (int x = tid; x < 40 * 1536; x += nT) {
    int g = x % 3, y = x / 3, c = y % 512, jp = y / 512;
    long long r = (long long)(g * 512 + c) * (In + Hn) + 2 * jp;
    U[OFF_WIFPK + x] = pack_h2(ld_any(wi, r, bf), ld_any(wi, r + 1, bf));
  }
  for (int x = tid; x < 256 * 1536; x += nT) {
    int g = x % 3, y = x / 3, c = y % 512, kp = y / 512;
    long long r = (long long)(g * 512 + c) * (In + Hn) + Hn + 2 * kp;
    U[OFF_WIPREVPK + x] = pack_h2(ld_any(wi, r, bf), ld_any(wi, r + 1, bf));
  }
  for (int x = tid; x < 512 * 1536; x += nT) {
    int i = x / 1536, m = x % 1536;
    wsf[OFF_WIPT + x] = ld_any(wi, (long long)m * (In + Hn) + Hn + i, bf);
  }
  for (int x = tid; x < G3; x += nT) wsf[OFF_BI + x] = ld_any(gbi, x, bf);
  for (int x = tid; x < G3; x += nT) wsf[OFF_BH + x] = ld_any(gbh, x, bf);
  for (int x = tid; x < Cn; x += nT) wsf[OFF_B1 + x] = ld_any(kb1, x, bf);
  for (int x = tid; x < LOCn * Kn; x += nT) wsf[OFF_LW + x] = ld_any(lcw, x, bf);
  for (int x = tid; x < 256 * LOCn; x += nT) wsf[OFF_PW + x] = ld_any(lpw, x, bf);
  for (int x = tid; x < 256 * LOCn; x += nT) wsf[OFF_DW + x] = ld_any(dw, x, bf);
  for (int x = tid; x < 256; x += nT) wsf[OFF_DB + x] = ld_any(ddb, x, bf);
  for (int x = tid; x < 256; x += nT) wsf[OFF_AGG + x] = ld_any(aggw, x, bf);
  for (int x = tid; x < Pn; x += nT) wsf[OFF_PRI + x] = ld_any(pri, x, bf);
}

__global__ __launch_bounds__(1024) void k_encw(const void* __restrict__ enc_,
                                               const float* __restrict__ wsf,
                                               unsigned* __restrict__ U) {
  const int b = blockIdx.x >> 2, chunk = blockIdx.x & 3;
  const int bf = ((const int*)(wsf + OFF_FLAG))[0];
  const int tid = threadIdx.x;
  const int r = tid >> 8, m0 = tid & 255;
  const int s0 = chunk * 64 + r * 16;
  const float* WiPT = wsf + OFF_WIPT;
  for (int g6 = 0; g6 < 6; ++g6) {
    int m = m0 + (g6 << 8);
    float acc[16];
    #pragma unroll
    for (int j = 0; j < 16; ++j) acc[j] = 0.f;
    #pragma unroll 4
    for (int i = 0; i < In; ++i) {
      float w = WiPT[(size_t)i * G3 + m];
      #pragma unroll
      for (int j = 0; j < 16; ++j)
        acc[j] = fmaf(w, ld_any(enc_, ((long long)b * Sn + (s0 + j)) * In + i, bf), acc[j]);
    }
    int cc = m & 511, gg = m >> 9;
    unsigned* dst = U + OFF_ENCW + (size_t)b * 128 * G3;
    #pragma unroll
    for (int jj = 0; jj < 8; ++jj)
      dst[(size_t)(((s0 >> 1) + jj) * 512 + cc) * 3 + gg] = pack_h2(acc[2 * jj], acc[2 * jj + 1]);
  }
}

// ---- 4-way split kernel, fence-free exchange ----
__global__ __launch_bounds__(1024, 4) void k_split(
    const void* __restrict__ mask_, const void* __restrict__ gt_,
    const float* __restrict__ wsf, unsigned* __restrict__ UW,
    void* __restrict__ out_) {
  const int b = blockIdx.x >> 2;
  const int j = blockIdx.x & 3;
  const int tid = threadIdx.x;
  const int bf = ((const int*)(wsf + OFF_FLAG))[0];

  const float* BI = wsf + OFF_BI;
  const float* BH = wsf + OFF_BH;
  const float* B1 = wsf + OFF_B1;
  const float* lw = wsf + OFF_LW;
  const float* Pw = wsf + OFF_PW;
  const float* Dw = wsf + OFF_DW;
  const float* dbv = wsf + OFF_DB;
  const float* agg = wsf + OFF_AGG;
  const float* prw = wsf + OFF_PRI;
  const unsigned* U = UW;
  const unsigned* encwB = U + OFF_ENCW + (size_t)b * 128 * G3;
  unsigned* XH = UW + OFF_XH + b * 256;
  unsigned* TP = UW + OFF_TP + b * 4096;
  unsigned* XE = UW + OFF_XE + b * 256;
  unsigned* FLG = UW + OFF_FLG + b * 32;

  __shared__ __align__(16) float sA[280];
  __shared__ __align__(16) unsigned sAH[128];
  __shared__ __align__(16) unsigned sXfH[40];
  __shared__ __align__(16) unsigned sHH[256];
  __shared__ __align__(16) unsigned sHsl[64];
  __shared__ __align__(16) unsigned sT1H[256];
  __shared__ __align__(16) float sHfC[128];
  __shared__ __align__(16) float sP[6 * 8 * 128];
  __shared__ __align__(16) float sG6[768];
  __shared__ __align__(16) float sFLo[512];
  __shared__ __align__(16) float sFDo[512];
  __shared__ __align__(16) float sPriL[64];
  __shared__ __align__(16) float sDk[176];
  __shared__ __align__(16) float sMask[256];
  __shared__ float sRed2[8];

  for (int x = tid; x < 280; x += 1024) sA[x] = 0.f;
  for (int x = tid; x < 128; x += 1024) { sAH[x] = 0u; sHfC[x & 127] = 0.f; }
  for (int x = tid; x < 256; x += 1024) { sHH[x] = 0u;
    sMask[x] = ld_any(mask_, (long long)b * Sn + x, bf); }
  if (tid == 0) { sA[10] = 1.f; sAH[0] = pack_h2(1.f, 0.f); }
  if (tid < 40) sXfH[tid] = pack_h2(ld_any(gt_, (long long)b * Tn * Hn + 2 * tid, bf),
                                    ld_any(gt_, (long long)b * Tn * Hn + 2 * tid + 1, bf));
  __syncthreads();

  for (int t = 0; t < Tn; ++t) {
    const unsigned ep = (unsigned)(t + 1);
    // ---- S1: gate dots, c-range [128j,128j+128), 8-way split-k ----
    {
      const int ks = tid >> 7, cl = tid & 127;
      const int c = (j << 7) + cl;
      float xr = 0.f, xz = 0.f, xn = 0.f, hr = 0.f, hz = 0.f, hn = 0.f;
      const unsigned* pf = U + OFF_WIFPK + 3 * c;
      #pragma unroll
      for (int jp = ks * 5; jp < ks * 5 + 5; ++jp) {
        unsigned a = sXfH[jp];
        xr = dot2f(pf[jp * G3], a, xr);
        xz = dot2f(pf[jp * G3 + 1], a, xz);
        xn = dot2f(pf[jp * G3 + 2], a, xn);
      }
      const unsigned* pe = encwB + 3 * c;
      #pragma unroll 4
      for (int kp = ks * 16; kp < ks * 16 + 16; ++kp) {
        unsigned a = sAH[kp];              // wave-uniform: skip exact-zero alpha pairs
        if (a) {
          xr = dot2f(pe[kp * G3], a, xr);
          xz = dot2f(pe[kp * G3 + 1], a, xz);
          xn = dot2f(pe[kp * G3 + 2], a, xn);
        }
      }
      const unsigned* ph = U + OFF_WHPK + 3 * c;
      #pragma unroll 4
      for (int kp = ks * 32; kp < ks * 32 + 32; ++kp) {
        unsigned a = sHH[kp];
        hr = dot2f(ph[kp * G3], a, hr);
        hz = dot2f(ph[kp * G3 + 1], a, hz);
        hn = dot2f(ph[kp * G3 + 2], a, hn);
      }
      sP[(0 * 8 + ks) * 128 + cl] = xr;
      sP[(1 * 8 + ks) * 128 + cl] = xz;
      sP[(2 * 8 + ks) * 128 + cl] = xn;
      sP[(3 * 8 + ks) * 128 + cl] = hr;
      sP[(4 * 8 + ks) * 128 + cl] = hz;
      sP[(5 * 8 + ks) * 128 + cl] = hn;
    }
    __syncthreads();
    if (tid < 768) {
      int g = tid >> 7, cl = tid & 127;
      float s = 0.f;
      #pragma unroll
      for (int ks = 0; ks < 8; ++ks) s += sP[(g * 8 + ks) * 128 + cl];
      sG6[tid] = s;
    }
    __syncthreads();
    // ---- S2: gates (pack h-pairs via shuffle) | prior conv | loc conv ----
    if (tid < 128) {
      int cl = tid, c = (j << 7) + cl;
      float xr = sG6[cl] + BI[c];
      float xz = sG6[128 + cl] + BI[512 + c];
      float xn = sG6[256 + cl] + BI[1024 + c];
      float hr = sG6[384 + cl] + BH[c];
      float hz = sG6[512 + cl] + BH[512 + c];
      float hn = sG6[640 + cl] + BH[1024 + c];
      float r = fast_sigmoid(xr + hr);
      float z = fast_sigmoid(xz + hz);
      float n = fast_tanh(xn + r * hn);
      float hN = (1.f - z) * n + z * sHfC[cl];
      sHfC[cl] = hN;
      float nb = __shfl_xor(hN, 1, 64);
      if (!(tid & 1)) sHsl[tid >> 1] = pack_h2(hN, nb);
    } else if (tid >= 192 && tid < 256) {
      int sl = tid - 192;
      float acc = 0.f;
      #pragma unroll
      for (int k = 0; k < Pn; ++k) acc = fmaf(prw[k], sA[(j << 6) + sl + k], acc);
      sPriL[sl] = acc;
    } else if (tid >= 512) {
      int idx = tid - 512;
      int l = __builtin_amdgcn_readfirstlane(idx >> 6), sl = idx & 63;
      float acc = 0.f;
      #pragma unroll
      for (int k = 0; k < Kn; ++k) acc = fmaf(lw[l * Kn + k], sA[(j << 6) + sl + k], acc);
      sFLo[l * 64 + sl] = acc;
    }
    __syncthreads();
    // ---- S3: t1 partials from OWN h-slice + h-slice publish; flag A ----
    {
      const int c = tid & 511, kh = tid >> 9;
      const unsigned* m1 = U + OFF_W1PK + (unsigned)(j * 64 + kh * 32) * 512 + c;
      float acc = 0.f;
      #pragma unroll 4
      for (int kp = 0; kp < 32; ++kp)
        acc = dot2f(m1[kp * 512], sHsl[kh * 32 + kp], acc);
      st_dev(&TP[(j * 2 + kh) * 512 + c], __float_as_uint(acc));
    }
    if (tid < 64) st_dev(&XH[(j << 6) + tid], sHsl[tid]);
    __syncthreads();   // per-wave vmcnt(0) drain => all stores globally visible
    if (tid == 0) st_dev(&FLG[j], ep);
    if (tid < 4) {
      while (ld_dev(&FLG[tid]) < ep) __builtin_amdgcn_s_sleep(1);
    }
    __syncthreads();
    // ---- S4: load full h; t1 = tanh(b1 + sum of 8 partials), pack ----
    if (tid < 256) sHH[tid] = ld_dev(&XH[tid]);
    if (tid < 512) {
      float a = B1[tid];
      #pragma unroll
      for (int p = 0; p < 8; ++p) a += __uint_as_float(ld_dev(&TP[p * 512 + tid]));
      float tv = fast_tanh(a);
      float nb = __shfl_xor(tv, 1, 64);
      if (!(tid & 1)) sT1H[tid >> 1] = pack_h2(tv, nb);
    }
    __syncthreads();
    // ---- S5: dkern = W2 t1 (replicated, split-k quarters) ----
    if (tid < 672) {
      int kq = tid / 168, j2 = tid - kq * 168;
      const unsigned* m2 = U + OFF_W2PK + kq * 64 * 168 + j2;
      float acc = 0.f;
      #pragma unroll 4
      for (int kp = 0; kp < 64; ++kp)
        acc = dot2f(m2[kp * 168], sT1H[kq * 64 + kp], acc);
      sP[tid] = acc;
    }
    __syncthreads();
    if (tid < 168) sDk[tid] = sP[tid] + sP[tid + 168] + sP[tid + 336] + sP[tid + 504];
    __syncthreads();
    // ---- S6: dynamic conv for own s-range ----
    if (tid < 512) {
      int l = __builtin_amdgcn_readfirstlane(tid >> 6), sl = tid & 63;
      float acc = 0.f;
      #pragma unroll
      for (int k = 0; k < Kn; ++k) acc = fmaf(sDk[l * Kn + k], sA[(j << 6) + sl + k], acc);
      sFDo[l * 64 + sl] = acc;
    }
    __syncthreads();
    // ---- S7: scorer partials, 16 c-slices x 64 s ----
    {
      const int sl = tid & 63;
      const int slice = __builtin_amdgcn_readfirstlane(tid >> 6);
      float fl[LOCn], fd[LOCn];
      #pragma unroll
      for (int l = 0; l < LOCn; ++l) { fl[l] = sFLo[l * 64 + sl]; fd[l] = sFDo[l * 64 + sl]; }
      float e = 0.f;
      const int c0 = slice << 4;
      for (int c = c0; c < c0 + 16; ++c) {
        float sc = dbv[c];
        #pragma unroll
        for (int l = 0; l < LOCn; ++l) {
          sc = fmaf(Pw[c * LOCn + l], fl[l], sc);
          sc = fmaf(Dw[c * LOCn + l], fd[l], sc);
        }
        e = fmaf(agg[c], fast_tanh(sc), e);
      }
      sP[slice * 64 + sl] = e;
    }
    __syncthreads();
    // ---- R7: energy publish; flag B ----
    if (tid < 64) {
      float E = 0.f;
      #pragma unroll
      for (int q = 0; q < 16; ++q) E += sP[q * 64 + tid];
      E += fast_log(sPriL[tid] + 1e-5f);
      if (!(sMask[(j << 6) + tid] > 0.f)) E = -__builtin_inff();
      st_dev(&XE[(j << 6) + tid], __float_as_uint(E));
    }
    __builtin_amdgcn_s_waitcnt(0);   // wave 0: XE stores visible before flag
    if (tid == 0) st_dev(&FLG[16 + j], ep);
    if (tid < 4) {
      while (ld_dev(&FLG[16 + tid]) < ep) __builtin_amdgcn_s_sleep(1);
    }
    __syncthreads();
    // ---- S8: softmax (replicated) + alpha + output ----
    float eV = -__builtin_inff(), exv = 0.f;
    if (tid < 256) {
      eV = __uint_as_float(ld_dev(&XE[tid]));
      float m = eV;
      #pragma unroll
      for (int off = 32; off > 0; off >>= 1) m = fmaxf(m, __shfl_xor(m, off, 64));
      if ((tid & 63) == 0) sRed2[tid >> 6] = m;
    }
    __syncthreads();
    if (tid < 256) {
      float M = fmaxf(fmaxf(sRed2[0], sRed2[1]), fmaxf(sRed2[2], sRed2[3]));
      exv = fast_exp(eV - M);
      float ssum = exv;
      #pragma unroll
      for (int off = 32; off > 0; off >>= 1) ssum += __shfl_xor(ssum, off, 64);
      if ((tid & 63) == 0) sRed2[4 + (tid >> 6)] = ssum;
    } else if (tid >= 512 && tid < 552 && t + 1 < Tn) {
      int i = tid - 512;
      sXfH[i] = pack_h2(ld_any(gt_, ((long long)b * Tn + t + 1) * Hn + 2 * i, bf),
                        ld_any(gt_, ((long long)b * Tn + t + 1) * Hn + 2 * i + 1, bf));
    }
    __syncthreads();
    if (tid < 256) {
      float Z = sRed2[4] + sRed2[5] + sRed2[6] + sRed2[7];
      float a = exv * __builtin_amdgcn_rcpf(Z);
      sA[10 + tid] = a;
      float nb = __shfl_xor(a, 1, 64);
      if (!(tid & 1)) sAH[tid >> 1] = pack_h2(a, nb);
    }
    __syncthreads();
    if (tid >= 256 && tid < 320) {
      int s = (j << 6) + (tid - 256);
      float a = sA[10 + s];
      size_t oi = ((size_t)b * Tn + t) * Sn + s;
      if (bf) ((__hip_bfloat16*)out_)[oi] = __float2bfloat16(a);
      else ((float*)out_)[oi] = a;
    }
    __syncthreads();
  }
}

// ---- fallback: single-block-per-batch kernel (R3) ----
__global__ __launch_bounds__(1024) void k_single(
    const void* __restrict__ enc_, const void* __restrict__ mask_,
    const void* __restrict__ gt_, const float* __restrict__ wsf,
    const unsigned* __restrict__ U, void* __restrict__ out_, int use_encw) {
  const int b = blockIdx.x;
  const int tid = threadIdx.x;
  const int bf = ((const int*)(wsf + OFF_FLAG))[0];
  const float* BI = wsf + OFF_BI;
  const float* BH = wsf + OFF_BH;
  const float* B1 = wsf + OFF_B1;
  const float* lw = wsf + OFF_LW;
  const float* Pw = wsf + OFF_PW;
  const float* Dw = wsf + OFF_DW;
  const float* dbv = wsf + OFF_DB;
  const float* agg = wsf + OFF_AGG;
  const float* prw = wsf + OFF_PRI;

  __shared__ __align__(16) float sA[280];
  __shared__ __align__(16) unsigned sAH[128];
  __shared__ __align__(16) unsigned sXfH[40];
  __shared__ __align__(16) unsigned sPrevH[256];
  __shared__ __align__(16) float sHf[512];
  __shared__ __align__(16) unsigned sHH[256];
  __shared__ __align__(16) unsigned sT1H[256];
  __shared__ __align__(16) float sXr[512], sXz[512], sXn[512];
  __shared__ __align__(16) float sHr[512], sHz[512], sHnM[512], sHnP[512];
  __shared__ __align__(16) float sDk[176];
  __shared__ __align__(16) float sFL[LOCn][Sn];
  __shared__ __align__(16) float sFD[LOCn][Sn];
  __shared__ __align__(16) float sPri[Sn];
  __shared__ __align__(16) float sMask[Sn];
  __shared__ __align__(16) float sR[1024];
  __shared__ float sRed2[8];

  for (int x = tid; x < 280; x += 1024) sA[x] = 0.f;
  for (int x = tid; x < 128; x += 1024) sAH[x] = 0u;
  for (int x = tid; x < Cn; x += 1024) sHf[x] = 0.f;
  for (int x = tid; x < 256; x += 1024) sHH[x] = 0u;
  for (int x = tid; x < Sn; x += 1024) sMask[x] = ld_any(mask_, (long long)b * Sn + x, bf);
  if (tid == 0) { sA[Kn / 2] = 1.f; sAH[0] = pack_h2(1.f, 0.f); }
  if (tid < Hn) ((_Float16*)sXfH)[tid] = (_Float16)ld_any(gt_, (long long)b * Tn * Hn + tid, bf);
  __syncthreads();

  const int Pp = use_encw ? 132 : 0;
  const int n3 = 256 - Pp;
  const int n1 = use_encw ? 128 : 256;
  const unsigned* encwB = U + OFF_ENCW + (size_t)b * 128 * G3;

  for (int t = 0; t < Tn; ++t) {
    if (!use_encw) {
      int i = tid & (In - 1);
      int s0 = (tid >> 9) << 7;
      float acc = 0.f;
      if (bf) {
        const unsigned short* enc = (const unsigned short*)enc_ + (size_t)b * Sn * In + i;
        #pragma unroll 4
        for (int s = s0; s < s0 + 128; ++s)
          acc = fmaf(__uint_as_float(((unsigned)enc[(size_t)s * In]) << 16), sA[10 + s], acc);
      } else {
        const float* enc = (const float*)enc_ + (size_t)b * Sn * In + i;
        #pragma unroll 4
        for (int s = s0; s < s0 + 128; ++s)
          acc = fmaf(enc[(size_t)s * In], sA[10 + s], acc);
      }
      sR[tid] = acc;
      __syncthreads();
      if (tid < In) ((_Float16*)sPrevH)[tid] = (_Float16)(sR[tid] + sR[tid + In]);
      __syncthreads();
    }
    if (tid < Cn) {
      const int c = tid;
      float xr = BI[c], xz = BI[c + 512], xn = BI[c + 1024];
      {
        const unsigned* pf = U + OFF_WIFPK + 3 * c;
        #pragma unroll 4
        for (int jp = 0; jp < 40; ++jp) {
          unsigned a = sXfH[jp];
          xr = dot2f(pf[jp * G3], a, xr);
          xz = dot2f(pf[jp * G3 + 1], a, xz);
          xn = dot2f(pf[jp * G3 + 2], a, xn);
        }
      }
      {
        const unsigned* pm = use_encw ? (encwB + 3 * c) : (U + OFF_WIPREVPK + 3 * c);
        const unsigned* aSrc = use_encw ? sAH : sPrevH;
        #pragma unroll 4
        for (int kp = 0; kp < n1; ++kp) {
          unsigned a = aSrc[kp];
          xr = dot2f(pm[kp * G3], a, xr);
          xz = dot2f(pm[kp * G3 + 1], a, xz);
          xn = dot2f(pm[kp * G3 + 2], a, xn);
        }
      }
      {
        float hp = 0.f;
        const unsigned* ph = U + OFF_WHPK + 3 * c + 2;
        #pragma unroll 4
        for (int kp = n3; kp < 256; ++kp)
          hp = dot2f(ph[kp * G3], sHH[kp], hp);
        sHnP[c] = hp;
      }
      sXr[c] = xr; sXz[c] = xz; sXn[c] = xn;
    } else {
      const int c = tid - Cn;
      float hr = BH[c], hz = BH[c + 512], hn = BH[c + 1024];
      const unsigned* ph = U + OFF_WHPK + 3 * c;
      #pragma unroll 4
      for (int kp = 0; kp < n3; ++kp) {
        unsigned a = sHH[kp];
        hr = dot2f(ph[kp * G3], a, hr);
        hz = dot2f(ph[kp * G3 + 1], a, hz);
        hn = dot2f(ph[kp * G3 + 2], a, hn);
      }
      #pragma unroll 4
      for (int kp = n3; kp < 256; ++kp) {
        unsigned a = sHH[kp];
        hr = dot2f(ph[kp * G3], a, hr);
        hz = dot2f(ph[kp * G3 + 1], a, hz);
      }
      sHr[c] = hr; sHz[c] = hz; sHnM[c] = hn;
    }
    __syncthreads();
    if (tid < Cn) {
      int c = tid;
      float r = fast_sigmoid(sXr[c] + sHr[c]);
      float z = fast_sigmoid(sXz[c] + sHz[c]);
      float n = fast_tanh(sXn[c] + r * (sHnM[c] + sHnP[c]));
      float hN = (1.f - z) * n + z * sHf[c];
      sHf[c] = hN;
      ((_Float16*)sHH)[c] = (_Float16)hN;
    } else {
      int j = tid - Cn;
      #pragma unroll
      for (int rr = 0; rr < 4; ++rr) {
        int idx = j + (rr << 9);
        int l = idx >> 8, s = idx & (Sn - 1);
        float acc = 0.f;
        #pragma unroll
        for (int k = 0; k < Kn; ++k) acc = fmaf(lw[l * Kn + k], sA[s + k], acc);
        sFL[l][s] = acc;
      }
      if (j < Sn) {
        float acc = 0.f;
        #pragma unroll
        for (int k = 0; k < Pn; ++k) acc = fmaf(prw[k], sA[j + k], acc);
        sPri[j] = acc;
      }
    }
    __syncthreads();
    {
      int c = tid & (Cn - 1), half = tid >> 9;
      const unsigned* m1 = U + OFF_W1PK + half * 128 * 512 + c;
      float acc = 0.f;
      #pragma unroll 4
      for (int kp = 0; kp < 128; ++kp)
        acc = dot2f(m1[kp * 512], sHH[half * 128 + kp], acc);
      sR[tid] = acc;
    }
    __syncthreads();
    if (tid < Cn) ((_Float16*)sT1H)[tid] = (_Float16)fast_tanh(B1[tid] + sR[tid] + sR[tid + Cn]);
    __syncthreads();
    if (tid < 672) {
      int kq = tid / 168, j = tid - kq * 168;
      const unsigned* m2 = U + OFF_W2PK + kq * 64 * 168 + j;
      float acc = 0.f;
      #pragma unroll 4
      for (int kp = 0; kp < 64; ++kp)
        acc = dot2f(m2[kp * 168], sT1H[kq * 64 + kp], acc);
      sR[tid] = acc;
    }
    __syncthreads();
    if (tid < LOCn * Kn) sDk[tid] = sR[tid] + sR[tid + 168] + sR[tid + 336] + sR[tid + 504];
    __syncthreads();
    #pragma unroll
    for (int rr = 0; rr < 2; ++rr) {
      int idx = tid + (rr << 10);
      int l = idx >> 8, s = idx & (Sn - 1);
      float acc = 0.f;
      #pragma unroll
      for (int k = 0; k < Kn; ++k) acc = fmaf(sDk[l * Kn + k], sA[s + k], acc);
      sFD[l][s] = acc;
    }
    __syncthreads();
    {
      const int q = __builtin_amdgcn_readfirstlane(tid >> 8);
      const int s = tid & (Sn - 1);
      float fl0[LOCn], fd0[LOCn];
      #pragma unroll
      for (int l = 0; l < LOCn; ++l) { fl0[l] = sFL[l][s]; fd0[l] = sFD[l][s]; }
      float e = 0.f;
      const int c0 = q << 6;
      for (int c = c0; c < c0 + 64; ++c) {
        float sc = dbv[c];
        #pragma unroll
        for (int l = 0; l < LOCn; ++l) {
          sc = fmaf(Pw[c * LOCn + l], fl0[l], sc);
          sc = fmaf(Dw[c * LOCn + l], fd0[l], sc);
        }
        e = fmaf(agg[c], fast_tanh(sc), e);
      }
      sR[tid] = e;
    }
    __syncthreads();
    float eVal = -__builtin_inff();
    if (tid < Sn) {
      eVal = sR[tid] + sR[tid + 256] + sR[tid + 512] + sR[tid + 768];
      eVal += fast_log(sPri[tid] + 1e-5f);
      if (!(sMask[tid] > 0.f)) eVal = -__builtin_inff();
      float m = eVal;
      #pragma unroll
      for (int off = 32; off > 0; off >>= 1) m = fmaxf(m, __shfl_xor(m, off, 64));
      if ((tid & 63) == 0) sRed2[tid >> 6] = m;
    }
    __syncthreads();
    float exv = 0.f;
    if (tid < Sn) {
      float M = fmaxf(fmaxf(sRed2[0], sRed2[1]), fmaxf(sRed2[2], sRed2[3]));
      exv = fast_exp(eVal - M);
      float ssum = exv;
      #pragma unroll
      for (int off = 32; off > 0; off >>= 1) ssum += __shfl_xor(ssum, off, 64);
      if ((tid & 63) == 0) sRed2[4 + (tid >> 6)] = ssum;
    }
    __syncthreads();
    if (tid < Sn) {
      float Z = sRed2[4] + sRed2[5] + sRed2[6] + sRed2[7];
      float a = exv * __builtin_amdgcn_rcpf(Z);
      sA[10 + tid] = a;
      ((_Float16*)sAH)[tid] = (_Float16)a;
      size_t oi = ((size_t)b * Tn + t) * Sn + tid;
      if (bf) ((__hip_bfloat16*)out_)[oi] = __float2bfloat16(a);
      else ((float*)out_)[oi] = a;
    } else if (tid >= 512 && tid < 512 + Hn && t + 1 < Tn) {
      int j = tid - 512;
      ((_Float16*)sXfH)[j] = (_Float16)ld_any(gt_, ((long long)b * Tn + t + 1) * Hn + j, bf);
    }
    __syncthreads();
  }
}

extern "C" void kernel_launch(void* const* d_in, const int* in_sizes, int n_in,
                              void* d_out, int out_size, void* d_ws, size_t ws_size,
                              hipStream_t stream) {
  float* wsf = (float*)d_ws;
  unsigned* U = (unsigned*)d_ws;
  const int use_encw = (ws_size >= (size_t)WS_END_ENCW * 4u) ? 1 : 0;
  const int use_split = (ws_size >= (size_t)WS_END_ALL * 4u) ? 1 : 0;
  k_flag<<<1, 64, 0, stream>>>(d_in[1], wsf);
  k_prep<<<1024, 256, 0, stream>>>(d_in[3], d_in[4], d_in[5], d_in[6],
                                   d_in[7], d_in[8], d_in[9], d_in[10],
                                   d_in[11], d_in[12], d_in[13], d_in[14],
                                   d_in[15], wsf, U);
  if (use_split) {
    k_encw<<<256, 1024, 0, stream>>>(d_in[0], wsf, U);
    k_zero<<<8, 256, 0, stream>>>(U);
    k_split<<<256, 1024, 0, stream>>>(d_in[1], d_in[2], wsf, U, d_out);
  } else {
    if (use_encw) k_encw<<<256, 1024, 0, stream>>>(d_in[0], wsf, U);
    k_single<<<Bn, 1024, 0, stream>>>(d_in[0], d_in[1], d_in[2], wsf, U, d_out, use_encw);
  }
}